// Round 11
// baseline (1297.784 us; speedup 1.0000x reference)
//
#include <hip/hip_runtime.h>

#define NN 10000
#define NE 100000
#define NG 64
#define RCUT 5.0f
#define FEPS 1e-9f
#define PREF 0.63245553203367586f   /* sqrt(2/RCUT) */
#define PI_R 0.62831853071795864f   /* pi/RCUT */
#define INVK 0.17677669529663687f   /* 1/sqrt(32) */
#define NXB ((NE+255)/256)          /* 391 */

static __device__ __forceinline__ float sigm(float z){ return 1.0f/(1.0f+__expf(-z)); }

// ================= CSR build =================
__global__ __launch_bounds__(256) void csr_count(const int* __restrict__ eidx,
                                                 int* __restrict__ deg)
{
    int e = blockIdx.x*256 + threadIdx.x;
    if (e < NE) atomicAdd(&deg[eidx[NE + e]], 1);
}

__global__ __launch_bounds__(256) void csr_scan(const int* __restrict__ deg,
                                                int* __restrict__ roff,
                                                int* __restrict__ woff)
{
    __shared__ int part[256];
    const int tid = threadIdx.x;
    const int C = 40;                 // 256*40 = 10240 >= NN
    int base = tid*C;
    int s = 0;
    for (int j=0;j<C;j++){ int idx=base+j; if (idx<NN) s += deg[idx]; }
    part[tid] = s; __syncthreads();
    for (int off=1; off<256; off<<=1){
        int v = part[tid];
        int add = (tid>=off) ? part[tid-off] : 0;
        __syncthreads();
        part[tid] = v + add;
        __syncthreads();
    }
    int run = (tid==0) ? 0 : part[tid-1];
    for (int j=0;j<C;j++){
        int idx = base+j;
        if (idx < NN){ roff[idx]=run; woff[idx]=run; run += deg[idx]; }
    }
    if (tid==255) roff[NN] = run;
}

__global__ __launch_bounds__(256) void csr_scatter(const int* __restrict__ eidx,
                                                   int* __restrict__ woff,
                                                   int* __restrict__ elist,
                                                   int* __restrict__ einv)
{
    int e = blockIdx.x*256 + threadIdx.x;
    if (e < NE){
        int pos = atomicAdd(&woff[eidx[NE + e]], 1);
        elist[pos] = e;
        einv[e] = pos;
    }
}

// ================= per-edge forward: msg_rl (128) + Ybuf (16), CSR order =====
__global__ __launch_bounds__(256) void edge_compute(
    const float* __restrict__ pos, const int* __restrict__ eidx,
    const float* __restrict__ shifts, const int* __restrict__ species,
    const float* __restrict__ Wz,
    const float* __restrict__ rW1, const float* __restrict__ rb1,
    const float* __restrict__ rW2, const float* __restrict__ rb2,
    const float* __restrict__ rW3, const float* __restrict__ rb3,
    const int* __restrict__ einv, float* __restrict__ msg_rl,
    float* __restrict__ Ybuf)
{
    const int e = blockIdx.x*256 + threadIdx.x;
    if (e >= NE) return;
    const int s = eidx[e];
    const int t = eidx[NE + e];
    float vx = pos[3*t+0]-pos[3*s+0]+shifts[3*e+0];
    float vy = pos[3*t+1]-pos[3*s+1]+shifts[3*e+1];
    float vz = pos[3*t+2]-pos[3*s+2]+shifts[3*e+2];
    float r2 = vx*vx+vy*vy+vz*vz + FEPS;
    float r  = sqrtf(r2);
    float inv_r = 1.0f/r;
    float x = vx*inv_r, y = vy*inv_r, z = vz*inv_r;

    float tt = r*(1.0f/RCUT);
    float fc = 0.0f;
    if (r < RCUT){
        float t2=tt*tt, t3=t2*tt, t6=t3*t3;
        fc = 1.0f + t6*(-28.0f + tt*(48.0f - 21.0f*tt));
    }
    float inv_rp = 1.0f/(r+FEPS);
    float w = PREF*fc*inv_rp;
    float s1,c1; __sincosf(PI_R*r, &s1, &c1);
    float xr[8];
    {
        float sp_=0.f, sc=s1; const float c2=2.f*c1;
        #pragma unroll
        for(int m=0;m<8;m++){ xr[m]=sc*w; float nx=c2*sc-sp_; sp_=sc; sc=nx; }
    }
    const int sp = species[s];
    const int slot = einv[e];
    float* mb = msg_rl + (size_t)slot*128;
    #pragma unroll
    for (int l=0;l<4;l++){
        const float* W1 = rW1 + l*256;  const float* B1 = rb1 + l*32;
        float h1[32];
        #pragma unroll
        for(int k=0;k<32;k++){
            float a = B1[k];
            #pragma unroll
            for(int q=0;q<8;q++) a += xr[q]*W1[k*8+q];
            h1[k] = a*sigm(a);
        }
        const float* W2 = rW2 + l*1024; const float* B2 = rb2 + l*32;
        float h2[32];
        #pragma unroll
        for(int j=0;j<32;j++){
            float a = B2[j];
            #pragma unroll
            for(int k=0;k<32;k++) a += h1[k]*W2[j*32+k];
            h2[j] = a*sigm(a);
        }
        const float* W3 = rW3 + l*1024; const float* B3 = rb3 + l*32;
        #pragma unroll
        for(int j=0;j<32;j++){
            float a = B3[j];
            #pragma unroll
            for(int k=0;k<32;k++) a += h2[k]*W3[j*32+k];
            mb[l*32+j] = a * Wz[j*3+sp];
        }
    }
    float* Yp = Ybuf + (size_t)slot*16;
    Yp[0]  = 1.0f;
    Yp[1]  = 1.7320508f*x;  Yp[2]  = 1.7320508f*y;  Yp[3]  = 1.7320508f*z;
    Yp[4]  = 3.8729833f*x*y; Yp[5] = 3.8729833f*y*z;
    Yp[6]  = 1.1180340f*(3.f*z*z-1.f);
    Yp[7]  = 3.8729833f*x*z; Yp[8] = 1.9364917f*(x*x-y*y);
    Yp[9]  = 2.0916501f*y*(3.f*x*x-y*y);
    Yp[10] = 10.246951f*x*y*z;
    Yp[11] = 1.6201852f*y*(5.f*z*z-1.f);
    Yp[12] = 1.3228757f*(5.f*z*z*z-3.f*z);
    Yp[13] = 1.6201852f*x*(5.f*z*z-1.f);
    Yp[14] = 5.1234754f*z*(x*x-y*y);
    Yp[15] = 2.0916501f*x*(x*x-3.f*y*y);
}

// ================= gather: one wave per node -> AdA node-major ===============
__global__ __launch_bounds__(256) void gather(
    const float* __restrict__ msg_rl, const float* __restrict__ Ybuf,
    const int* __restrict__ roff, float* __restrict__ AdA)
{
    const int w = (blockIdx.x*256 + threadIdx.x) >> 6;   // node id
    const int lane = threadIdx.x & 63;
    if (w >= NN) return;
    const int k = lane & 31;
    const bool hi = (lane >= 32);
    float a0=0,a1=0,a2=0,a3=0,a4=0,a5=0,a6=0,a7=0;
    const int beg = roff[w], end = roff[w+1];
    for (int idx=beg; idx<end; ++idx){
        const float* b = msg_rl + (size_t)idx*128;
        const float* Yp = Ybuf + (size_t)idx*16;
        float rl1 = b[32+k];
        float rl2 = b[64+k];
        float rl3 = b[96+k];
        if (!hi){
            float rl0 = b[k];
            a0 += rl0;
            a1 += rl1*Yp[2];
            a2 += rl2*Yp[4];
            a3 += rl2*Yp[6];
            a4 += rl2*Yp[8];
            a5 += rl3*Yp[10];
            a6 += rl3*Yp[12];
            a7 += rl3*Yp[14];
        } else {
            a0 += rl1*Yp[1];
            a1 += rl1*Yp[3];
            a2 += rl2*Yp[5];
            a3 += rl2*Yp[7];
            a4 += rl3*Yp[9];
            a5 += rl3*Yp[11];
            a6 += rl3*Yp[13];
            a7 += rl3*Yp[15];
        }
    }
    // i = i0+2m  ->  addr w*512 + m*64 + lane  (coalesced)
    float av[8] = {a0,a1,a2,a3,a4,a5,a6,a7};
    #pragma unroll
    for (int m=0;m<8;m++) AdA[(size_t)w*512 + m*64 + lane] = av[m];
}

// ================= node pass: in-place A -> dA (node-major) ==================
__global__ __launch_bounds__(256) void node_pass_ip(
    float* __restrict__ AdA, const int* __restrict__ species,
    const float* __restrict__ mixW, const float* __restrict__ symW1,
    const float* __restrict__ symW2, const float* __restrict__ eW,
    const float* __restrict__ ebp, const float* __restrict__ e0W,
    const float* __restrict__ e0b, float* __restrict__ E_node)
{
    const int n = blockIdx.x*256 + threadIdx.x;
    const int i = blockIdx.y;
    const int l = (i==0)?0 : (i<4)?1 : (i<9)?2 : 3;
    if (n >= NN) return;
    const int sp = species[n];

    float a[32];
    #pragma unroll
    for(int k=0;k<32;k++) a[k] = AdA[(size_t)n*512 + i*32 + k];

    const float* M = mixW + l*1024;
    float A2[32];
    #pragma unroll
    for(int o=0;o<32;o++){
        float acc = 0.f;
        #pragma unroll
        for(int k=0;k<32;k++) acc += a[k]*M[o*32+k];
        A2[o] = acc*INVK;
    }
    const float nl = (l==0)?1.0f : (l==1)?0.57735027f : (l==2)?0.44721360f : 0.37796447f;
    float ce = 0.f;
    float dA2[32];
    #pragma unroll
    for(int o=0;o<32;o++){
        float w2v = symW2[(sp*4+l)*32+o];
        float ew  = eW[o];
        float c = A2[o]*A2[o]*nl*w2v;
        float g = 2.f*A2[o]*nl*w2v;
        if (i==0){ float w1v = symW1[sp*32+o]; c += w1v*A2[o]; g += w1v; }
        ce += c*ew;
        dA2[o] = g*ew;
    }
    if (i==0) ce += ebp[0] + e0W[sp] + e0b[0];

    #pragma unroll
    for(int k=0;k<32;k++){
        float acc = 0.f;
        #pragma unroll
        for(int o=0;o<32;o++) acc += dA2[o]*M[o*32+k];
        AdA[(size_t)n*512 + i*32 + k] = acc*INVK;
    }
    atomicAdd(&E_node[n], ce);
}

// ================= E binning =================
__global__ __launch_bounds__(256) void ereduce(
    const float* __restrict__ E_node, const int* __restrict__ batch,
    float* __restrict__ out)
{
    int n = blockIdx.x*256 + threadIdx.x;
    const int lane = threadIdx.x & 63;
    float v = (n < NN) ? E_node[n] : 0.f;
    int   b = (n < NN) ? batch[n]  : -1;
    #pragma unroll
    for (int d=1; d<64; d<<=1){
        float pv = __shfl_down(v, d, 64);
        int   pb = __shfl_down(b, d, 64);
        if ((lane + d) < 64 && pb == b) v += pv;
    }
    int prevb = __shfl_up(b, 1, 64);
    if (n < NN && (lane == 0 || prevb != b)) atomicAdd(&out[b], v);
}

// ================= K1: angular backward, one wave per node ===================
__global__ __launch_bounds__(256) void dy_scatter(
    const int* __restrict__ roff, float* msg_rl,
    const float* __restrict__ Ybuf, const float* __restrict__ AdA,
    float* __restrict__ dubuf)
{
    const int w = (blockIdx.x*256 + threadIdx.x) >> 6;
    const int lane = threadIdx.x & 63;
    if (w >= NN) return;
    const int k = lane & 31;
    const bool hi = (lane >= 32);
    float da[8];
    #pragma unroll
    for (int m=0;m<8;m++) da[m] = AdA[(size_t)w*512 + m*64 + lane]; // dA[i0+2m][k]
    const int beg = roff[w], end = roff[w+1];
    for (int idx=beg; idx<end; ++idx){
        float* b = msg_rl + (size_t)idx*128;
        const float* Yp = Ybuf + (size_t)idx*16;
        float rl0 = b[k], rl1 = b[32+k], rl2 = b[64+k], rl3 = b[96+k];
        float x = Yp[1]*0.57735026919f, y = Yp[2]*0.57735026919f, z = Yp[3]*0.57735026919f;
        float p[8];
        if (!hi){
            p[0]=da[0]*rl0; p[1]=da[1]*rl1; p[2]=da[2]*rl2; p[3]=da[3]*rl2;
            p[4]=da[4]*rl2; p[5]=da[5]*rl3; p[6]=da[6]*rl3; p[7]=da[7]*rl3;
        } else {
            p[0]=da[0]*rl1; p[1]=da[1]*rl1; p[2]=da[2]*rl2; p[3]=da[3]*rl2;
            p[4]=da[4]*rl3; p[5]=da[5]*rl3; p[6]=da[6]*rl3; p[7]=da[7]*rl3;
        }
        #pragma unroll
        for (int m=0;m<8;m++){
            float v = p[m];
            v += __shfl_xor(v, 1, 64);
            v += __shfl_xor(v, 2, 64);
            v += __shfl_xor(v, 4, 64);
            v += __shfl_xor(v, 8, 64);
            v += __shfl_xor(v,16, 64);
            p[m] = v;    // dY[i0+2m], replicated within half
        }
        float y_[8];
        #pragma unroll
        for (int m=0;m<8;m++) y_[m] = Yp[(hi?1:0)+2*m];
        float pl0, pl1, pl2, pl3;
        if (!hi){
            pl0 = da[0]*y_[0];
            pl1 = da[1]*y_[1];
            pl2 = da[2]*y_[2] + da[3]*y_[3] + da[4]*y_[4];
            pl3 = da[5]*y_[5] + da[6]*y_[6] + da[7]*y_[7];
        } else {
            pl0 = 0.f;
            pl1 = da[0]*y_[0] + da[1]*y_[1];
            pl2 = da[2]*y_[2] + da[3]*y_[3];
            pl3 = da[4]*y_[4] + da[5]*y_[5] + da[6]*y_[6] + da[7]*y_[7];
        }
        pl0 += __shfl_xor(pl0, 32, 64);
        pl1 += __shfl_xor(pl1, 32, 64);
        pl2 += __shfl_xor(pl2, 32, 64);
        pl3 += __shfl_xor(pl3, 32, 64);
        float dux, duy, duz;
        if (!hi){
            dux = 3.8729833f*(y*p[2] + x*p[4]) + 10.246951f*z*(y*p[5] + x*p[7]);
            duy = 1.7320508f*p[1] + 3.8729833f*(x*p[2] - y*p[4])
                + 10.246951f*z*(x*p[5] - y*p[7]);
            duz = 6.7082039f*z*p[3] + 10.246951f*x*y*p[5]
                + 1.3228757f*(15.f*z*z-3.f)*p[6] + 5.1234754f*(x*x-y*y)*p[7];
        } else {
            dux = 1.7320508f*p[0] + 3.8729833f*z*p[3] + 12.549901f*x*y*p[4]
                + 1.6201852f*(5.f*z*z-1.f)*p[6] + 6.2749503f*(x*x-y*y)*p[7];
            duy = 3.8729833f*z*p[2] + 6.2749503f*(x*x-y*y)*p[4]
                + 1.6201852f*(5.f*z*z-1.f)*p[5] - 12.549901f*x*y*p[7];
            duz = 1.7320508f*p[1] + 3.8729833f*(y*p[2] + x*p[3])
                + 16.201852f*z*(y*p[5] + x*p[6]);
        }
        dux += __shfl_xor(dux, 32, 64);
        duy += __shfl_xor(duy, 32, 64);
        duz += __shfl_xor(duz, 32, 64);
        if (!hi){ b[k] = pl0; b[32+k] = pl1; }
        else    { b[64+k] = pl2; b[96+k] = pl3; }
        if (lane == 0){
            dubuf[(size_t)idx*4+0] = dux;
            dubuf[(size_t)idx*4+1] = duy;
            dubuf[(size_t)idx*4+2] = duz;
        }
    }
}

// ================= K2: radial backward per (slot,l) ==========================
// Round-9 staged structure (proven 152 VGPR, no spill) + float4 LDS reads
// (ds_read_b128) with 4 independent partial accumulators per dot product.
// Stages remain DISJOINT (round-10 C+D fusion spilled at 256 VGPR).
__global__ __launch_bounds__(256) void radial_bwd(
    const float* __restrict__ pos, const int* __restrict__ eidx,
    const float* __restrict__ shifts, const int* __restrict__ species,
    const float* __restrict__ Wz,
    const float* __restrict__ rW1, const float* __restrict__ rb1,
    const float* __restrict__ rW2, const float* __restrict__ rb2,
    const float* __restrict__ rW3,
    const float* __restrict__ msg_rl /* = dRlZ */,
    const int* __restrict__ elist, float* __restrict__ grbuf)
{
    __shared__ __align__(16) float W1L[256];    // [k][q]  = W1[k*8+q]
    __shared__ __align__(16) float W1T[256];    // [m][k]  = W1[k*8+m]
    __shared__ __align__(16) float W2L[1024];   // [j][k]  = W2[j*32+k]
    __shared__ __align__(16) float W2T[1024];   // [k][j]  = W2[j*32+k]
    __shared__ __align__(16) float W3T[1024];   // [k][j]  = W3[j*32+k]
    __shared__ float B1L[32], B2L[32], WzL[96];

    const int l = blockIdx.y;
    const int tid = threadIdx.x;
    {
        const float* W1g = rW1 + l*256;
        const float* W2g = rW2 + l*1024;
        const float* W3g = rW3 + l*1024;
        { float v = W1g[tid]; W1L[tid] = v; W1T[(tid&7)*32 + (tid>>3)] = v; }
        #pragma unroll
        for (int i0=0;i0<4;i0++){
            int i = i0*256 + tid;
            float v2 = W2g[i]; W2L[i] = v2; W2T[(i&31)*32 + (i>>5)] = v2;
            float v3 = W3g[i]; W3T[(i&31)*32 + (i>>5)] = v3;
        }
        if (tid < 32){ B1L[tid] = rb1[l*32+tid]; B2L[tid] = rb2[l*32+tid]; }
        if (tid < 96) WzL[tid] = Wz[tid];
    }
    __syncthreads();

    const int idx = blockIdx.x*256 + tid;
    if (idx >= NE) return;
    const int e = elist[idx];
    const int s = eidx[e];
    const int t = eidx[NE + e];
    float vx = pos[3*t+0]-pos[3*s+0]+shifts[3*e+0];
    float vy = pos[3*t+1]-pos[3*s+1]+shifts[3*e+1];
    float vz = pos[3*t+2]-pos[3*s+2]+shifts[3*e+2];
    float r2 = vx*vx+vy*vy+vz*vz + FEPS;
    float r  = sqrtf(r2);

    float tt = r*(1.0f/RCUT);
    float fc = 0.0f, dfc = 0.0f;
    if (r < RCUT){
        float t2=tt*tt, t3=t2*tt, t5=t3*t2, t6=t5*tt, t7=t6*tt;
        fc  = 1.0f + t6*(-28.0f + tt*(48.0f - 21.0f*tt));
        dfc = (-168.f*t5 + 336.f*t6 - 168.f*t7)*(1.0f/RCUT);
    }
    float inv_rp = 1.0f/(r+FEPS);
    float w = PREF*fc*inv_rp;
    float s1,c1; __sincosf(PI_R*r, &s1, &c1);
    float sn[8], cn[8];
    {
        float sp_=0.f, sc=s1, cp_=1.f, cc=c1; const float c2=2.f*c1;
        #pragma unroll
        for(int m=0;m<8;m++){
            sn[m]=sc; cn[m]=cc;
            float nx=c2*sc-sp_; sp_=sc; sc=nx;
            float ncx=c2*cc-cp_; cp_=cc; cc=ncx;
        }
    }

    // helper: 32-dot from a float4 row base against a register array, 4 chains
    #define DOT32(ROWPTR, VEC, OUT) { \
        const float4* _row = (const float4*)(ROWPTR); \
        float _a0=0.f,_a1=0.f,_a2=0.f,_a3=0.f; \
        _Pragma("unroll") \
        for(int _c=0;_c<8;_c++){ \
            float4 _rv = _row[_c]; \
            _a0 += (VEC)[4*_c+0]*_rv.x; _a1 += (VEC)[4*_c+1]*_rv.y; \
            _a2 += (VEC)[4*_c+2]*_rv.z; _a3 += (VEC)[4*_c+3]*_rv.w; } \
        OUT = (_a0+_a1)+(_a2+_a3); }

    // ---- stage A: g3[k] = dot(dRl, W3T row k) ----
    float g3[32];
    {
        float dRl[32];
        const int sp = species[s];
        const float* db_ = msg_rl + (size_t)idx*128 + l*32;
        #pragma unroll
        for(int j=0;j<32;j++) dRl[j] = db_[j] * WzL[j*3+sp];
        #pragma unroll
        for(int k=0;k<32;k++){
            float o; DOT32(&W3T[k*32], dRl, o);
            g3[k] = o;
        }
    }
    // ---- stage B: h1, df1 (W1L rows: 8 floats = 2 float4) ----
    float h1[32], df1[32];
    {
        float xr[8];
        #pragma unroll
        for(int q=0;q<8;q++) xr[q] = sn[q]*w;
        #pragma unroll
        for(int k=0;k<32;k++){
            const float4* row = (const float4*)&W1L[k*8];
            float4 u0 = row[0], u1 = row[1];
            float a = B1L[k]
                + (xr[0]*u0.x + xr[1]*u0.y + xr[2]*u0.z + xr[3]*u0.w)
                + (xr[4]*u1.x + xr[5]*u1.y + xr[6]*u1.z + xr[7]*u1.w);
            float sg=sigm(a); h1[k]=a*sg; df1[k]=sg*(1.f + a*(1.f-sg));
        }
    }
    // ---- stage C: dz2 overwrites g3 (z2 dot via W2L rows) ----
    #pragma unroll
    for(int j=0;j<32;j++){
        float o; DOT32(&W2L[j*32], h1, o);
        float a = B2L[j] + o;
        float sg=sigm(a);
        g3[j] *= sg*(1.f + a*(1.f-sg));          // g3 is now dz2
    }
    // ---- stage D: dz1 overwrites h1 (W2T rows) ----
    #pragma unroll
    for(int k=0;k<32;k++){
        float o; DOT32(&W2T[k*32], g3, o);
        h1[k] = o*df1[k];                         // h1 is now dz1
    }
    // ---- stage E: gr (W1T rows: 32 contiguous) ----
    float gr = 0.f;
    #pragma unroll
    for(int m=0;m<8;m++){
        float o; DOT32(&W1T[m*32], h1, o);
        float b  = PREF*sn[m]*inv_rp;
        float db = PREF*((float)(m+1)*PI_R*cn[m]*(r+FEPS) - sn[m])*inv_rp*inv_rp;
        gr += o*(db*fc + b*dfc);
    }
    #undef DOT32
    grbuf[(size_t)l*NE + idx] = gr;
}

// ================= K3: final force assembly ==================================
__global__ __launch_bounds__(256) void force_finish(
    const float* __restrict__ pos, const int* __restrict__ eidx,
    const float* __restrict__ shifts, const int* __restrict__ elist,
    const float* __restrict__ dubuf, const float* __restrict__ grbuf,
    float* __restrict__ F)
{
    const int idx0 = blockIdx.x*256 + threadIdx.x;
    const bool valid = (idx0 < NE);
    const int idx = valid ? idx0 : (NE-1);
    const int e = elist[idx];
    const int s = eidx[e];
    const int t = eidx[NE + e];
    float vx = pos[3*t+0]-pos[3*s+0]+shifts[3*e+0];
    float vy = pos[3*t+1]-pos[3*s+1]+shifts[3*e+1];
    float vz = pos[3*t+2]-pos[3*s+2]+shifts[3*e+2];
    float r2 = vx*vx+vy*vy+vz*vz + FEPS;
    float r  = sqrtf(r2);
    float inv_r = 1.0f/r;
    float x = vx*inv_r, y = vy*inv_r, z = vz*inv_r;
    float gr = grbuf[idx] + grbuf[NE+idx] + grbuf[2*NE+idx] + grbuf[3*NE+idx];
    float dux = dubuf[(size_t)idx*4+0];
    float duy = dubuf[(size_t)idx*4+1];
    float duz = dubuf[(size_t)idx*4+2];
    float udd = x*dux + y*duy + z*duz;
    float gx = gr*x + (dux - x*udd)*inv_r;
    float gy = gr*y + (duy - y*udd)*inv_r;
    float gz = gr*z + (duz - z*udd)*inv_r;
    if (!valid){ gx=0.f; gy=0.f; gz=0.f; }
    if (valid){
        atomicAdd(&F[3*s+0], gx); atomicAdd(&F[3*s+1], gy); atomicAdd(&F[3*s+2], gz);
    }
    const int lane = threadIdx.x & 63;
    int key = valid ? t : -1;
    float rx=gx, ry=gy, rz=gz;
    #pragma unroll
    for (int d=1; d<64; d<<=1){
        float px = __shfl_down(rx, d, 64);
        float py = __shfl_down(ry, d, 64);
        float pz = __shfl_down(rz, d, 64);
        int   pk = __shfl_down(key, d, 64);
        if ((lane + d) < 64 && pk == key){ rx+=px; ry+=py; rz+=pz; }
    }
    int pk = __shfl_up(key, 1, 64);
    if (valid && (lane == 0 || pk != key)){
        atomicAdd(&F[3*t+0], -rx); atomicAdd(&F[3*t+1], -ry); atomicAdd(&F[3*t+2], -rz);
    }
}

// ================= fallback kernels (round-1 style, ~41 MB ws) ===============
__global__ __launch_bounds__(256) void edge_fwd_fb(
    const float* __restrict__ pos, const int* __restrict__ eidx,
    const float* __restrict__ shifts, const int* __restrict__ species,
    const float* __restrict__ Wz,
    const float* __restrict__ rW1, const float* __restrict__ rb1,
    const float* __restrict__ rW2, const float* __restrict__ rb2,
    const float* __restrict__ rW3, const float* __restrict__ rb3,
    float* __restrict__ A_t)
{
    const int e = blockIdx.x*256 + threadIdx.x;
    const int l = blockIdx.y;
    if (e >= NE) return;
    const int s = eidx[e];
    const int t = eidx[NE + e];
    float vx = pos[3*t+0]-pos[3*s+0]+shifts[3*e+0];
    float vy = pos[3*t+1]-pos[3*s+1]+shifts[3*e+1];
    float vz = pos[3*t+2]-pos[3*s+2]+shifts[3*e+2];
    float r2 = vx*vx+vy*vy+vz*vz + FEPS;
    float r  = sqrtf(r2);
    float inv_r = 1.0f/r;
    float x = vx*inv_r, y = vy*inv_r, z = vz*inv_r;
    float tt = r*(1.0f/RCUT);
    float fcv = 0.0f;
    if (r < RCUT){
        float t2=tt*tt, t3=t2*tt, t6=t3*t3;
        fcv = 1.0f + t6*(-28.0f + tt*(48.0f - 21.0f*tt));
    }
    float inv_rp = 1.0f/(r+FEPS);
    float w = PREF*fcv*inv_rp;
    float s1,c1; __sincosf(PI_R*r, &s1, &c1);
    float xr[8];
    {
        float sp_=0.f, sc=s1; const float c2=2.f*c1;
        #pragma unroll
        for(int m=0;m<8;m++){ xr[m]=sc*w; float nx=c2*sc-sp_; sp_=sc; sc=nx; }
    }
    const float* W1 = rW1 + l*256;  const float* B1 = rb1 + l*32;
    float h1[32];
    #pragma unroll
    for(int k=0;k<32;k++){
        float a = B1[k];
        #pragma unroll
        for(int q=0;q<8;q++) a += xr[q]*W1[k*8+q];
        h1[k] = a*sigm(a);
    }
    const float* W2 = rW2 + l*1024; const float* B2 = rb2 + l*32;
    float h2[32];
    #pragma unroll
    for(int j=0;j<32;j++){
        float a = B2[j];
        #pragma unroll
        for(int k=0;k<32;k++) a += h1[k]*W2[j*32+k];
        h2[j] = a*sigm(a);
    }
    const float* W3 = rW3 + l*1024; const float* B3 = rb3 + l*32;
    const int sp = species[s];
    float RlZ[32];
    #pragma unroll
    for(int j=0;j<32;j++){
        float a = B3[j];
        #pragma unroll
        for(int k=0;k<32;k++) a += h2[k]*W3[j*32+k];
        RlZ[j] = a * Wz[j*3+sp];
    }
    #define ACCI(I, YV) { const float yv=(YV); \
        _Pragma("unroll") \
        for(int k=0;k<32;k++) atomicAdd(&A_t[((I)*32+k)*NN + t], RlZ[k]*yv); }
    if (l==0){
        ACCI(0, 1.0f)
    } else if (l==1){
        ACCI(1, 1.7320508f*x) ACCI(2, 1.7320508f*y) ACCI(3, 1.7320508f*z)
    } else if (l==2){
        ACCI(4, 3.8729833f*x*y) ACCI(5, 3.8729833f*y*z)
        ACCI(6, 1.1180340f*(3.f*z*z-1.f)) ACCI(7, 3.8729833f*x*z)
        ACCI(8, 1.9364917f*(x*x-y*y))
    } else {
        ACCI(9,  2.0916501f*y*(3.f*x*x-y*y))
        ACCI(10, 10.246951f*x*y*z)
        ACCI(11, 1.6201852f*y*(5.f*z*z-1.f))
        ACCI(12, 1.3228757f*(5.f*z*z*z-3.f*z))
        ACCI(13, 1.6201852f*x*(5.f*z*z-1.f))
        ACCI(14, 5.1234754f*z*(x*x-y*y))
        ACCI(15, 2.0916501f*x*(x*x-3.f*y*y))
    }
    #undef ACCI
}

__global__ __launch_bounds__(256) void node_pass_fb(
    const float* __restrict__ A_t, const int* __restrict__ species,
    const float* __restrict__ mixW, const float* __restrict__ symW1,
    const float* __restrict__ symW2, const float* __restrict__ eW,
    const float* __restrict__ ebp, const float* __restrict__ e0W,
    const float* __restrict__ e0b,
    float* __restrict__ dA_t, float* __restrict__ E_node)
{
    const int n = blockIdx.x*256 + threadIdx.x;
    const int i = blockIdx.y;
    const int l = (i==0)?0 : (i<4)?1 : (i<9)?2 : 3;
    if (n >= NN) return;
    const int sp = species[n];
    float a[32];
    #pragma unroll
    for(int k=0;k<32;k++) a[k] = A_t[(i*32+k)*NN + n];
    const float* M = mixW + l*1024;
    float A2[32];
    #pragma unroll
    for(int o=0;o<32;o++){
        float acc = 0.f;
        #pragma unroll
        for(int k=0;k<32;k++) acc += a[k]*M[o*32+k];
        A2[o] = acc*INVK;
    }
    const float nl = (l==0)?1.0f : (l==1)?0.57735027f : (l==2)?0.44721360f : 0.37796447f;
    float ce = 0.f;
    float dA2[32];
    #pragma unroll
    for(int o=0;o<32;o++){
        float w2v = symW2[(sp*4+l)*32+o];
        float ew  = eW[o];
        float c = A2[o]*A2[o]*nl*w2v;
        float g = 2.f*A2[o]*nl*w2v;
        if (i==0){ float w1v = symW1[sp*32+o]; c += w1v*A2[o]; g += w1v; }
        ce += c*ew;
        dA2[o] = g*ew;
    }
    if (i==0) ce += ebp[0] + e0W[sp] + e0b[0];
    #pragma unroll
    for(int k=0;k<32;k++){
        float acc = 0.f;
        #pragma unroll
        for(int o=0;o<32;o++) acc += dA2[o]*M[o*32+k];
        dA_t[(i*32+k)*NN + n] = acc*INVK;
    }
    atomicAdd(&E_node[n], ce);
}

__global__ __launch_bounds__(256) void edge_bwd_fb(
    const float* __restrict__ pos, const int* __restrict__ eidx,
    const float* __restrict__ shifts, const int* __restrict__ species,
    const float* __restrict__ Wz,
    const float* __restrict__ rW1, const float* __restrict__ rb1,
    const float* __restrict__ rW2, const float* __restrict__ rb2,
    const float* __restrict__ rW3, const float* __restrict__ rb3,
    const float* __restrict__ dA_t, float* __restrict__ F)
{
    const int e = blockIdx.x*256 + threadIdx.x;
    const int l = blockIdx.y;
    if (e >= NE) return;
    const int s = eidx[e];
    const int t = eidx[NE + e];
    float vx = pos[3*t+0]-pos[3*s+0]+shifts[3*e+0];
    float vy = pos[3*t+1]-pos[3*s+1]+shifts[3*e+1];
    float vz = pos[3*t+2]-pos[3*s+2]+shifts[3*e+2];
    float r2 = vx*vx+vy*vy+vz*vz + FEPS;
    float r  = sqrtf(r2);
    float inv_r = 1.0f/r;
    float x = vx*inv_r, y = vy*inv_r, z = vz*inv_r;
    float tt = r*(1.0f/RCUT);
    float fc = 0.0f, dfc = 0.0f;
    if (r < RCUT){
        float t2=tt*tt, t3=t2*tt, t5=t3*t2, t6=t5*tt, t7=t6*tt;
        fc  = 1.0f + t6*(-28.0f + tt*(48.0f - 21.0f*tt));
        dfc = (-168.f*t5 + 336.f*t6 - 168.f*t7)*(1.0f/RCUT);
    }
    float inv_rp = 1.0f/(r+FEPS);
    float w = PREF*fc*inv_rp;
    float s1,c1; __sincosf(PI_R*r, &s1, &c1);
    float sn[8], cn[8];
    {
        float sp_=0.f, sc=s1, cp_=1.f, cc=c1; const float c2=2.f*c1;
        #pragma unroll
        for(int m=0;m<8;m++){
            sn[m]=sc; cn[m]=cc;
            float nx=c2*sc-sp_; sp_=sc; sc=nx;
            float ncx=c2*cc-cp_; cp_=cc; cc=ncx;
        }
    }
    const float* W1 = rW1 + l*256;  const float* B1 = rb1 + l*32;
    float df1[32], h1[32];
    #pragma unroll
    for(int k=0;k<32;k++){
        float a = B1[k];
        #pragma unroll
        for(int q=0;q<8;q++) a += (sn[q]*w)*W1[k*8+q];
        float sg=sigm(a); h1[k]=a*sg; df1[k]=sg*(1.f + a*(1.f-sg));
    }
    const float* W2 = rW2 + l*1024; const float* B2 = rb2 + l*32;
    float df2[32], h2[32];
    #pragma unroll
    for(int j=0;j<32;j++){
        float a = B2[j];
        #pragma unroll
        for(int k=0;k<32;k++) a += h1[k]*W2[j*32+k];
        float sg=sigm(a); h2[j]=a*sg; df2[j]=sg*(1.f + a*(1.f-sg));
    }
    const float* W3 = rW3 + l*1024; const float* B3 = rb3 + l*32;
    const int sp = species[s];
    float RlZ[32];
    #pragma unroll
    for(int j=0;j<32;j++){
        float a = B3[j];
        #pragma unroll
        for(int k=0;k<32;k++) a += h2[k]*W3[j*32+k];
        RlZ[j] = a * Wz[j*3+sp];
    }
    float dRlZ[32];
    #pragma unroll
    for(int k=0;k<32;k++) dRlZ[k]=0.f;
    float dux=0.f, duy=0.f, duz=0.f;
    #define ROW(I, YV, DX, DY, DZ) { \
        const float yv=(YV); float dY=0.f; \
        _Pragma("unroll") \
        for(int k=0;k<32;k++){ \
            float g = dA_t[((I)*32+k)*NN + t]; \
            dRlZ[k] += g*yv; dY += g*RlZ[k]; } \
        dux += dY*(DX); duy += dY*(DY); duz += dY*(DZ); }
    if (l==0){
        ROW(0, 1.0f, 0.f,0.f,0.f)
    } else if (l==1){
        ROW(1, 1.7320508f*x, 1.7320508f, 0.f, 0.f)
        ROW(2, 1.7320508f*y, 0.f, 1.7320508f, 0.f)
        ROW(3, 1.7320508f*z, 0.f, 0.f, 1.7320508f)
    } else if (l==2){
        ROW(4, 3.8729833f*x*y, 3.8729833f*y, 3.8729833f*x, 0.f)
        ROW(5, 3.8729833f*y*z, 0.f, 3.8729833f*z, 3.8729833f*y)
        ROW(6, 1.1180340f*(3.f*z*z-1.f), 0.f, 0.f, 6.7082039f*z)
        ROW(7, 3.8729833f*x*z, 3.8729833f*z, 0.f, 3.8729833f*x)
        ROW(8, 1.9364917f*(x*x-y*y), 3.8729833f*x, -3.8729833f*y, 0.f)
    } else {
        ROW(9,  2.0916501f*y*(3.f*x*x-y*y), 12.549901f*x*y, 2.0916501f*(3.f*x*x-3.f*y*y), 0.f)
        ROW(10, 10.246951f*x*y*z, 10.246951f*y*z, 10.246951f*x*z, 10.246951f*x*y)
        ROW(11, 1.6201852f*y*(5.f*z*z-1.f), 0.f, 1.6201852f*(5.f*z*z-1.f), 16.201852f*y*z)
        ROW(12, 1.3228757f*(5.f*z*z*z-3.f*z), 0.f, 0.f, 1.3228757f*(15.f*z*z-3.f))
        ROW(13, 1.6201852f*x*(5.f*z*z-1.f), 1.6201852f*(5.f*z*z-1.f), 0.f, 16.201852f*x*z)
        ROW(14, 5.1234754f*z*(x*x-y*y), 10.246951f*x*z, -10.246951f*y*z, 5.1234754f*(x*x-y*y))
        ROW(15, 2.0916501f*x*(x*x-3.f*y*y), 2.0916501f*(3.f*x*x-3.f*y*y), -12.549901f*x*y, 0.f)
    }
    #undef ROW
    #pragma unroll
    for(int j=0;j<32;j++) dRlZ[j] *= Wz[j*3+sp];
    float dz2[32];
    #pragma unroll
    for(int k=0;k<32;k++){
        float a=0.f;
        #pragma unroll
        for(int j=0;j<32;j++) a += dRlZ[j]*W3[j*32+k];
        dz2[k] = a*df2[k];
    }
    float dz1[32];
    #pragma unroll
    for(int k=0;k<32;k++){
        float a=0.f;
        #pragma unroll
        for(int j=0;j<32;j++) a += dz2[j]*W2[j*32+k];
        dz1[k] = a*df1[k];
    }
    float gr = 0.f;
    #pragma unroll
    for(int m=0;m<8;m++){
        float a=0.f;
        #pragma unroll
        for(int k=0;k<32;k++) a += dz1[k]*W1[k*8+m];
        float b  = PREF*sn[m]*inv_rp;
        float db = PREF*((float)(m+1)*PI_R*cn[m]*(r+FEPS) - sn[m])*inv_rp*inv_rp;
        gr += a*(db*fc + b*dfc);
    }
    float udd = x*dux + y*duy + z*duz;
    float gx = gr*x + (dux - x*udd)*inv_r;
    float gy = gr*y + (duy - y*udd)*inv_r;
    float gz = gr*z + (duz - z*udd)*inv_r;
    atomicAdd(&F[3*t+0], -gx); atomicAdd(&F[3*t+1], -gy); atomicAdd(&F[3*t+2], -gz);
    atomicAdd(&F[3*s+0],  gx); atomicAdd(&F[3*s+1],  gy); atomicAdd(&F[3*s+2],  gz);
}

// ================= launcher =================
extern "C" void kernel_launch(void* const* d_in, const int* in_sizes, int n_in,
                              void* d_out, int out_size, void* d_ws, size_t ws_size,
                              hipStream_t stream)
{
    const float* pos    = (const float*)d_in[0];
    const int*   eidx   = (const int*)  d_in[1];
    const float* shifts = (const float*)d_in[2];
    const int*   spec   = (const int*)  d_in[3];
    const int*   batch  = (const int*)  d_in[4];
    const float* Wz     = (const float*)d_in[5];
    const float* rW1    = (const float*)d_in[6];
    const float* rb1    = (const float*)d_in[7];
    const float* rW2    = (const float*)d_in[8];
    const float* rb2    = (const float*)d_in[9];
    const float* rW3    = (const float*)d_in[10];
    const float* rb3    = (const float*)d_in[11];
    const float* mixW   = (const float*)d_in[12];
    const float* symW1  = (const float*)d_in[13];
    const float* symW2  = (const float*)d_in[14];
    const float* eW     = (const float*)d_in[15];
    const float* ebp    = (const float*)d_in[16];
    const float* e0W    = (const float*)d_in[17];
    const float* e0b    = (const float*)d_in[18];
    float* out = (float*)d_out;

    // ws: ints [deg NN | roff NN+1 | woff NN | elist NE | einv NE]
    //     floats [AdA 512*NN | E_node NN | msg_rl 128*NE | Ybuf 16*NE |
    //             dubuf 4*NE | grbuf 4*NE]   (total ~82.2 MB)
    const size_t INTS   = (size_t)(3*NN + 1 + 2*NE);
    const size_t FOFF   = ((INTS*4 + 255)/256)*256;
    const size_t NEEDED = FOFF +
        ((size_t)512*NN + NN + (size_t)128*NE + (size_t)16*NE +
         (size_t)4*NE + (size_t)4*NE)*4;

    if (ws_size >= NEEDED){
        int*   deg    = (int*)d_ws;
        int*   roff   = deg + NN;
        int*   woff   = roff + NN + 1;
        int*   elist  = woff + NN;
        int*   einv   = elist + NE;
        float* f0     = (float*)((char*)d_ws + FOFF);
        float* AdA    = f0;
        float* E_node = AdA + (size_t)512*NN;
        float* msg_rl = E_node + NN;
        float* Ybuf   = msg_rl + (size_t)128*NE;
        float* dubuf  = Ybuf + (size_t)16*NE;
        float* grbuf  = dubuf + (size_t)4*NE;

        hipMemsetAsync(deg, 0, NN*sizeof(int), stream);
        hipMemsetAsync(E_node, 0, NN*sizeof(float), stream);
        hipMemsetAsync(d_out, 0, (size_t)out_size*sizeof(float), stream);

        csr_count  <<<(NE+255)/256, 256, 0, stream>>>(eidx, deg);
        csr_scan   <<<1, 256, 0, stream>>>(deg, roff, woff);
        csr_scatter<<<(NE+255)/256, 256, 0, stream>>>(eidx, woff, elist, einv);
        edge_compute<<<(NE+255)/256, 256, 0, stream>>>(pos, eidx, shifts, spec, Wz,
                                                       rW1, rb1, rW2, rb2, rW3, rb3,
                                                       einv, msg_rl, Ybuf);
        gather<<<(NN*64+255)/256, 256, 0, stream>>>(msg_rl, Ybuf, roff, AdA);
        dim3 ng((NN+255)/256, 16);
        node_pass_ip<<<ng, 256, 0, stream>>>(AdA, spec, mixW, symW1, symW2,
                                             eW, ebp, e0W, e0b, E_node);
        ereduce<<<(NN+255)/256, 256, 0, stream>>>(E_node, batch, out);
        dy_scatter<<<(NN*64+255)/256, 256, 0, stream>>>(roff, msg_rl, Ybuf, AdA, dubuf);
        dim3 rg(NXB, 4);
        radial_bwd<<<rg, 256, 0, stream>>>(pos, eidx, shifts, spec, Wz,
                                           rW1, rb1, rW2, rb2, rW3,
                                           msg_rl, elist, grbuf);
        force_finish<<<NXB, 256, 0, stream>>>(pos, eidx, shifts, elist,
                                              dubuf, grbuf, out + NG);
    } else {
        // fallback: round-1 style (requires ~41 MB, known-good)
        float* A_t    = (float*)d_ws;
        float* E_node = A_t + (size_t)512*NN;
        float* dA_t   = E_node + NN;
        hipMemsetAsync(d_ws, 0, ((size_t)512*NN + NN)*sizeof(float), stream);
        hipMemsetAsync(d_out, 0, (size_t)out_size*sizeof(float), stream);
        dim3 eg((NE+255)/256, 4);
        edge_fwd_fb<<<eg, 256, 0, stream>>>(pos, eidx, shifts, spec, Wz,
                                            rW1, rb1, rW2, rb2, rW3, rb3, A_t);
        dim3 ng((NN+255)/256, 16);
        node_pass_fb<<<ng, 256, 0, stream>>>(A_t, spec, mixW, symW1, symW2,
                                             eW, ebp, e0W, e0b, dA_t, E_node);
        ereduce<<<(NN+255)/256, 256, 0, stream>>>(E_node, batch, out);
        edge_bwd_fb<<<eg, 256, 0, stream>>>(pos, eidx, shifts, spec, Wz,
                                            rW1, rb1, rW2, rb2, rW3, rb3,
                                            dA_t, out + NG);
    }
}

// Round 12
// 640.433 us; speedup vs baseline: 2.0264x; 2.0264x over previous
//
#include <hip/hip_runtime.h>

#define NN 10000
#define NE 100000
#define NG 64
#define RCUT 5.0f
#define FEPS 1e-9f
#define PREF 0.63245553203367586f   /* sqrt(2/RCUT) */
#define PI_R 0.62831853071795864f   /* pi/RCUT */
#define INVK 0.17677669529663687f   /* 1/sqrt(32) */
#define NXB ((NE+255)/256)          /* 391 */

static __device__ __forceinline__ float sigm(float z){ return 1.0f/(1.0f+__expf(-z)); }

// ================= CSR build =================
__global__ __launch_bounds__(256) void csr_count(const int* __restrict__ eidx,
                                                 int* __restrict__ deg)
{
    int e = blockIdx.x*256 + threadIdx.x;
    if (e < NE) atomicAdd(&deg[eidx[NE + e]], 1);
}

__global__ __launch_bounds__(256) void csr_scan(const int* __restrict__ deg,
                                                int* __restrict__ roff,
                                                int* __restrict__ woff)
{
    __shared__ int part[256];
    const int tid = threadIdx.x;
    const int C = 40;                 // 256*40 = 10240 >= NN
    int base = tid*C;
    int s = 0;
    for (int j=0;j<C;j++){ int idx=base+j; if (idx<NN) s += deg[idx]; }
    part[tid] = s; __syncthreads();
    for (int off=1; off<256; off<<=1){
        int v = part[tid];
        int add = (tid>=off) ? part[tid-off] : 0;
        __syncthreads();
        part[tid] = v + add;
        __syncthreads();
    }
    int run = (tid==0) ? 0 : part[tid-1];
    for (int j=0;j<C;j++){
        int idx = base+j;
        if (idx < NN){ roff[idx]=run; woff[idx]=run; run += deg[idx]; }
    }
    if (tid==255) roff[NN] = run;
}

__global__ __launch_bounds__(256) void csr_scatter(const int* __restrict__ eidx,
                                                   int* __restrict__ woff,
                                                   int* __restrict__ elist,
                                                   int* __restrict__ einv)
{
    int e = blockIdx.x*256 + threadIdx.x;
    if (e < NE){
        int pos = atomicAdd(&woff[eidx[NE + e]], 1);
        elist[pos] = e;
        einv[e] = pos;
    }
}

// ================= per-edge forward: msg records (CSR slot order) ============
// msg record (144 floats): [l*32+k] = Rl[l][k]*Zs[k]  (128), [128+lm] = Y[lm]
__global__ __launch_bounds__(256) void edge_compute(
    const float* __restrict__ pos, const int* __restrict__ eidx,
    const float* __restrict__ shifts, const int* __restrict__ species,
    const float* __restrict__ Wz,
    const float* __restrict__ rW1, const float* __restrict__ rb1,
    const float* __restrict__ rW2, const float* __restrict__ rb2,
    const float* __restrict__ rW3, const float* __restrict__ rb3,
    const int* __restrict__ einv, float* __restrict__ msg)
{
    const int e = blockIdx.x*256 + threadIdx.x;
    if (e >= NE) return;
    const int s = eidx[e];
    const int t = eidx[NE + e];
    float vx = pos[3*t+0]-pos[3*s+0]+shifts[3*e+0];
    float vy = pos[3*t+1]-pos[3*s+1]+shifts[3*e+1];
    float vz = pos[3*t+2]-pos[3*s+2]+shifts[3*e+2];
    float r2 = vx*vx+vy*vy+vz*vz + FEPS;
    float r  = sqrtf(r2);
    float inv_r = 1.0f/r;
    float x = vx*inv_r, y = vy*inv_r, z = vz*inv_r;

    float tt = r*(1.0f/RCUT);
    float fc = 0.0f;
    if (r < RCUT){
        float t2=tt*tt, t3=t2*tt, t6=t3*t3;
        fc = 1.0f + t6*(-28.0f + tt*(48.0f - 21.0f*tt));
    }
    float inv_rp = 1.0f/(r+FEPS);
    float w = PREF*fc*inv_rp;
    float s1,c1; __sincosf(PI_R*r, &s1, &c1);
    float xr[8];
    {
        float sp_=0.f, sc=s1; const float c2=2.f*c1;
        #pragma unroll
        for(int m=0;m<8;m++){ xr[m]=sc*w; float nx=c2*sc-sp_; sp_=sc; sc=nx; }
    }
    const int sp = species[s];
    float* mb = msg + (size_t)einv[e]*144;
    #pragma unroll
    for (int l=0;l<4;l++){
        const float* W1 = rW1 + l*256;  const float* B1 = rb1 + l*32;
        float h1[32];
        #pragma unroll
        for(int k=0;k<32;k++){
            float a = B1[k];
            #pragma unroll
            for(int q=0;q<8;q++) a += xr[q]*W1[k*8+q];
            h1[k] = a*sigm(a);
        }
        const float* W2 = rW2 + l*1024; const float* B2 = rb2 + l*32;
        float h2[32];
        #pragma unroll
        for(int j=0;j<32;j++){
            float a = B2[j];
            #pragma unroll
            for(int k=0;k<32;k++) a += h1[k]*W2[j*32+k];
            h2[j] = a*sigm(a);
        }
        const float* W3 = rW3 + l*1024; const float* B3 = rb3 + l*32;
        #pragma unroll
        for(int j=0;j<32;j++){
            float a = B3[j];
            #pragma unroll
            for(int k=0;k<32;k++) a += h2[k]*W3[j*32+k];
            mb[l*32+j] = a * Wz[j*3+sp];
        }
    }
    float* Yp = mb + 128;
    Yp[0]  = 1.0f;
    Yp[1]  = 1.7320508f*x;  Yp[2]  = 1.7320508f*y;  Yp[3]  = 1.7320508f*z;
    Yp[4]  = 3.8729833f*x*y; Yp[5] = 3.8729833f*y*z;
    Yp[6]  = 1.1180340f*(3.f*z*z-1.f);
    Yp[7]  = 3.8729833f*x*z; Yp[8] = 1.9364917f*(x*x-y*y);
    Yp[9]  = 2.0916501f*y*(3.f*x*x-y*y);
    Yp[10] = 10.246951f*x*y*z;
    Yp[11] = 1.6201852f*y*(5.f*z*z-1.f);
    Yp[12] = 1.3228757f*(5.f*z*z*z-3.f*z);
    Yp[13] = 1.6201852f*x*(5.f*z*z-1.f);
    Yp[14] = 5.1234754f*z*(x*x-y*y);
    Yp[15] = 2.0916501f*x*(x*x-3.f*y*y);
}

// ================= gather: one wave per node, sequential msg stream ==========
__global__ __launch_bounds__(256) void gather(
    const float* __restrict__ msg, const int* __restrict__ roff,
    float* __restrict__ A_t)
{
    const int w = (blockIdx.x*256 + threadIdx.x) >> 6;   // node id
    const int lane = threadIdx.x & 63;
    if (w >= NN) return;
    const int k = lane & 31;
    const bool hi = (lane >= 32);
    float a0=0,a1=0,a2=0,a3=0,a4=0,a5=0,a6=0,a7=0;
    const int beg = roff[w], end = roff[w+1];
    for (int idx=beg; idx<end; ++idx){
        const float* b = msg + (size_t)idx*144;
        float rl1 = b[32+k];
        float rl2 = b[64+k];
        float rl3 = b[96+k];
        const float* Yp = b + 128;
        if (!hi){
            float rl0 = b[k];
            a0 += rl0;
            a1 += rl1*Yp[2];
            a2 += rl2*Yp[4];
            a3 += rl2*Yp[6];
            a4 += rl2*Yp[8];
            a5 += rl3*Yp[10];
            a6 += rl3*Yp[12];
            a7 += rl3*Yp[14];
        } else {
            a0 += rl1*Yp[1];
            a1 += rl1*Yp[3];
            a2 += rl2*Yp[5];
            a3 += rl2*Yp[7];
            a4 += rl3*Yp[9];
            a5 += rl3*Yp[11];
            a6 += rl3*Yp[13];
            a7 += rl3*Yp[15];
        }
    }
    const int i0 = hi ? 1 : 0;
    A_t[((i0+ 0)*32+k)*NN + w] = a0;
    A_t[((i0+ 2)*32+k)*NN + w] = a1;
    A_t[((i0+ 4)*32+k)*NN + w] = a2;
    A_t[((i0+ 6)*32+k)*NN + w] = a3;
    A_t[((i0+ 8)*32+k)*NN + w] = a4;
    A_t[((i0+10)*32+k)*NN + w] = a5;
    A_t[((i0+12)*32+k)*NN + w] = a6;
    A_t[((i0+14)*32+k)*NN + w] = a7;
}

// ================= node pass =================
template<bool NM>
__global__ __launch_bounds__(256) void node_pass(
    const float* __restrict__ A_t, const int* __restrict__ species,
    const float* __restrict__ mixW, const float* __restrict__ symW1,
    const float* __restrict__ symW2, const float* __restrict__ eW,
    const float* __restrict__ ebp, const float* __restrict__ e0W,
    const float* __restrict__ e0b,
    float* __restrict__ dA, float* __restrict__ E_node)
{
    const int n = blockIdx.x*256 + threadIdx.x;
    const int i = blockIdx.y;
    const int l = (i==0)?0 : (i<4)?1 : (i<9)?2 : 3;
    if (n >= NN) return;
    const int sp = species[n];

    float a[32];
    #pragma unroll
    for(int k=0;k<32;k++) a[k] = A_t[(i*32+k)*NN + n];

    const float* M = mixW + l*1024;
    float A2[32];
    #pragma unroll
    for(int o=0;o<32;o++){
        float acc = 0.f;
        #pragma unroll
        for(int k=0;k<32;k++) acc += a[k]*M[o*32+k];
        A2[o] = acc*INVK;
    }
    const float nl = (l==0)?1.0f : (l==1)?0.57735027f : (l==2)?0.44721360f : 0.37796447f;
    float ce = 0.f;
    float dA2[32];
    #pragma unroll
    for(int o=0;o<32;o++){
        float w2v = symW2[(sp*4+l)*32+o];
        float ew  = eW[o];
        float c = A2[o]*A2[o]*nl*w2v;
        float g = 2.f*A2[o]*nl*w2v;
        if (i==0){ float w1v = symW1[sp*32+o]; c += w1v*A2[o]; g += w1v; }
        ce += c*ew;
        dA2[o] = g*ew;
    }
    if (i==0) ce += ebp[0] + e0W[sp] + e0b[0];

    #pragma unroll
    for(int k=0;k<32;k++){
        float acc = 0.f;
        #pragma unroll
        for(int o=0;o<32;o++) acc += dA2[o]*M[o*32+k];
        if (NM) dA[(size_t)n*512 + i*32 + k] = acc*INVK;
        else    dA[(i*32+k)*NN + n]          = acc*INVK;
    }
    atomicAdd(&E_node[n], ce);
}

// ================= E binning (batch sorted -> wave-segmented reduce) =========
__global__ __launch_bounds__(256) void ereduce(
    const float* __restrict__ E_node, const int* __restrict__ batch,
    float* __restrict__ out)
{
    int n = blockIdx.x*256 + threadIdx.x;
    const int lane = threadIdx.x & 63;
    float v = (n < NN) ? E_node[n] : 0.f;
    int   b = (n < NN) ? batch[n]  : -1;
    #pragma unroll
    for (int d=1; d<64; d<<=1){
        float pv = __shfl_down(v, d, 64);
        int   pb = __shfl_down(b, d, 64);
        if ((lane + d) < 64 && pb == b) v += pv;
    }
    int prevb = __shfl_up(b, 1, 64);
    if (n < NN && (lane == 0 || prevb != b)) atomicAdd(&out[b], v);
}

// ================= edge backward (per-l planes, XCD swizzle, LDS weights) ====
// NM=true : 1D grid NXB*4, bijective XCD-chunk remap; x=g>>2, l=g&3.
//           e=elist[idx]; dA node-major; per-(idx,l) force to fbuf.
// NM=false: fallback, 2D grid (x,l), e=idx, dA strided, direct atomics.
// Weights staged in LDS (row-major + transposed, SCALAR reads only —
// float4 LDS reads spill at 256 VGPR; uncapped launch_bounds to avoid the
// (256,3) spill pathology confirmed in rounds 3/5/7).
template<bool NM>
__global__ __launch_bounds__(256) void edge_bwd(
    const float* __restrict__ pos, const int* __restrict__ eidx,
    const float* __restrict__ shifts, const int* __restrict__ species,
    const float* __restrict__ Wz,
    const float* __restrict__ rW1, const float* __restrict__ rb1,
    const float* __restrict__ rW2, const float* __restrict__ rb2,
    const float* __restrict__ rW3, const float* __restrict__ rb3,
    const float* __restrict__ dA, const int* __restrict__ elist,
    float* __restrict__ fout)
{
    __shared__ float W1L[256], W1T[256];
    __shared__ float W2L[1024], W2T[1024];
    __shared__ float W3L[1024], W3T[1024];
    __shared__ float B1L[32], B2L[32], B3L[32], WzL[96];

    int xb, l;
    if (NM){
        const int nwg = NXB*4;            // 1564
        const int q = nwg/8, r = nwg%8;   // 195, 4
        const int bid = blockIdx.x;
        const int xcd = bid & 7, p = bid >> 3;
        const int g = (xcd < r ? xcd*(q+1) : r*(q+1) + (xcd-r)*q) + p;
        xb = g >> 2; l = g & 3;
    } else {
        xb = blockIdx.x; l = blockIdx.y;
    }
    const int tid = threadIdx.x;
    {
        const float* W1g = rW1 + l*256;
        const float* W2g = rW2 + l*1024;
        const float* W3g = rW3 + l*1024;
        { float v = W1g[tid]; W1L[tid] = v; W1T[(tid&7)*32 + (tid>>3)] = v; }
        #pragma unroll
        for (int i0=0;i0<4;i0++){
            int i = i0*256 + tid;
            float v2 = W2g[i]; W2L[i] = v2; W2T[(i&31)*32 + (i>>5)] = v2;
            float v3 = W3g[i]; W3L[i] = v3; W3T[(i&31)*32 + (i>>5)] = v3;
        }
        if (tid < 32){ B1L[tid] = rb1[l*32+tid]; B2L[tid] = rb2[l*32+tid];
                       B3L[tid] = rb3[l*32+tid]; }
        if (tid < 96) WzL[tid] = Wz[tid];
    }
    __syncthreads();

    const int idx = xb*256 + tid;
    if (idx >= NE) return;
    const int e = NM ? elist[idx] : idx;
    const int s = eidx[e];
    const int t = eidx[NE + e];
    float vx = pos[3*t+0]-pos[3*s+0]+shifts[3*e+0];
    float vy = pos[3*t+1]-pos[3*s+1]+shifts[3*e+1];
    float vz = pos[3*t+2]-pos[3*s+2]+shifts[3*e+2];
    float r2 = vx*vx+vy*vy+vz*vz + FEPS;
    float r  = sqrtf(r2);
    float inv_r = 1.0f/r;
    float x = vx*inv_r, y = vy*inv_r, z = vz*inv_r;

    float tt = r*(1.0f/RCUT);
    float fc = 0.0f, dfc = 0.0f;
    if (r < RCUT){
        float t2=tt*tt, t3=t2*tt, t5=t3*t2, t6=t5*tt, t7=t6*tt;
        fc  = 1.0f + t6*(-28.0f + tt*(48.0f - 21.0f*tt));
        dfc = (-168.f*t5 + 336.f*t6 - 168.f*t7)*(1.0f/RCUT);
    }
    float inv_rp = 1.0f/(r+FEPS);
    float w = PREF*fc*inv_rp;
    float s1,c1; __sincosf(PI_R*r, &s1, &c1);
    float sn[8], cn[8];
    {
        float sp_=0.f, sc=s1, cp_=1.f, cc=c1; const float c2=2.f*c1;
        #pragma unroll
        for(int m=0;m<8;m++){
            sn[m]=sc; cn[m]=cc;
            float nx=c2*sc-sp_; sp_=sc; sc=nx;
            float ncx=c2*cc-cp_; cp_=cc; cc=ncx;
        }
    }

    // forward, keeping silu-derivative factors (all LDS scalar reads)
    float df1[32], h1[32];
    #pragma unroll
    for(int k=0;k<32;k++){
        float a = B1L[k];
        #pragma unroll
        for(int q=0;q<8;q++) a += (sn[q]*w)*W1L[k*8+q];
        float sg=sigm(a); h1[k]=a*sg; df1[k]=sg*(1.f + a*(1.f-sg));
    }
    float df2[32], h2[32];
    #pragma unroll
    for(int j=0;j<32;j++){
        float a = B2L[j];
        #pragma unroll
        for(int k=0;k<32;k++) a += h1[k]*W2L[j*32+k];
        float sg=sigm(a); h2[j]=a*sg; df2[j]=sg*(1.f + a*(1.f-sg));
    }
    const int sp = species[s];
    float RlZ[32];
    #pragma unroll
    for(int j=0;j<32;j++){
        float a = B3L[j];
        #pragma unroll
        for(int k=0;k<32;k++) a += h2[k]*W3L[j*32+k];
        RlZ[j] = a * WzL[j*3+sp];
    }
    float dRlZ[32];
    #pragma unroll
    for(int k=0;k<32;k++) dRlZ[k]=0.f;
    float dux=0.f, duy=0.f, duz=0.f;
    #define ROW(I, YV, DX, DY, DZ) { \
        const float yv=(YV); float dY=0.f; \
        _Pragma("unroll") \
        for(int k=0;k<32;k++){ \
            float g = NM ? dA[(size_t)t*512 + (I)*32 + k] : dA[((I)*32+k)*NN + t]; \
            dRlZ[k] += g*yv; dY += g*RlZ[k]; } \
        dux += dY*(DX); duy += dY*(DY); duz += dY*(DZ); }
    if (l==0){
        ROW(0, 1.0f, 0.f,0.f,0.f)
    } else if (l==1){
        ROW(1, 1.7320508f*x, 1.7320508f, 0.f, 0.f)
        ROW(2, 1.7320508f*y, 0.f, 1.7320508f, 0.f)
        ROW(3, 1.7320508f*z, 0.f, 0.f, 1.7320508f)
    } else if (l==2){
        ROW(4, 3.8729833f*x*y, 3.8729833f*y, 3.8729833f*x, 0.f)
        ROW(5, 3.8729833f*y*z, 0.f, 3.8729833f*z, 3.8729833f*y)
        ROW(6, 1.1180340f*(3.f*z*z-1.f), 0.f, 0.f, 6.7082039f*z)
        ROW(7, 3.8729833f*x*z, 3.8729833f*z, 0.f, 3.8729833f*x)
        ROW(8, 1.9364917f*(x*x-y*y), 3.8729833f*x, -3.8729833f*y, 0.f)
    } else {
        ROW(9,  2.0916501f*y*(3.f*x*x-y*y), 12.549901f*x*y, 2.0916501f*(3.f*x*x-3.f*y*y), 0.f)
        ROW(10, 10.246951f*x*y*z, 10.246951f*y*z, 10.246951f*x*z, 10.246951f*x*y)
        ROW(11, 1.6201852f*y*(5.f*z*z-1.f), 0.f, 1.6201852f*(5.f*z*z-1.f), 16.201852f*y*z)
        ROW(12, 1.3228757f*(5.f*z*z*z-3.f*z), 0.f, 0.f, 1.3228757f*(15.f*z*z-3.f))
        ROW(13, 1.6201852f*x*(5.f*z*z-1.f), 1.6201852f*(5.f*z*z-1.f), 0.f, 16.201852f*x*z)
        ROW(14, 5.1234754f*z*(x*x-y*y), 10.246951f*x*z, -10.246951f*y*z, 5.1234754f*(x*x-y*y))
        ROW(15, 2.0916501f*x*(x*x-3.f*y*y), 2.0916501f*(3.f*x*x-3.f*y*y), -12.549901f*x*y, 0.f)
    }
    #undef ROW
    #pragma unroll
    for(int j=0;j<32;j++) dRlZ[j] *= WzL[j*3+sp];
    float dz2[32];
    #pragma unroll
    for(int k=0;k<32;k++){
        float a=0.f;
        #pragma unroll
        for(int j=0;j<32;j++) a += dRlZ[j]*W3T[k*32+j];
        dz2[k] = a*df2[k];
    }
    float dz1[32];
    #pragma unroll
    for(int k=0;k<32;k++){
        float a=0.f;
        #pragma unroll
        for(int j=0;j<32;j++) a += dz2[j]*W2T[k*32+j];
        dz1[k] = a*df1[k];
    }
    float gr = 0.f;
    #pragma unroll
    for(int m=0;m<8;m++){
        float a=0.f;
        #pragma unroll
        for(int k=0;k<32;k++) a += dz1[k]*W1T[m*32+k];
        float b  = PREF*sn[m]*inv_rp;
        float db = PREF*((float)(m+1)*PI_R*cn[m]*(r+FEPS) - sn[m])*inv_rp*inv_rp;
        gr += a*(db*fc + b*dfc);
    }
    float udd = x*dux + y*duy + z*duz;
    float gx = gr*x + (dux - x*udd)*inv_r;
    float gy = gr*y + (duy - y*udd)*inv_r;
    float gz = gr*z + (duz - z*udd)*inv_r;
    if (NM){
        fout[(l*3+0)*NE + idx] = gx;
        fout[(l*3+1)*NE + idx] = gy;
        fout[(l*3+2)*NE + idx] = gz;
    } else {
        atomicAdd(&fout[3*t+0], -gx); atomicAdd(&fout[3*t+1], -gy); atomicAdd(&fout[3*t+2], -gz);
        atomicAdd(&fout[3*s+0],  gx); atomicAdd(&fout[3*s+1],  gy); atomicAdd(&fout[3*s+2],  gz);
    }
}

// ================= force reduce: t-side gather (no atomics) ==================
__global__ __launch_bounds__(256) void freduce_t(
    const float* __restrict__ fbuf, const int* __restrict__ roff,
    float* __restrict__ F)
{
    int n = blockIdx.x*256 + threadIdx.x;
    if (n >= NN) return;
    float gx=0.f, gy=0.f, gz=0.f;
    const int beg = roff[n], end = roff[n+1];
    for (int idx=beg; idx<end; ++idx){
        gx += fbuf[0*NE+idx] + fbuf[3*NE+idx] + fbuf[6*NE+idx] + fbuf[ 9*NE+idx];
        gy += fbuf[1*NE+idx] + fbuf[4*NE+idx] + fbuf[7*NE+idx] + fbuf[10*NE+idx];
        gz += fbuf[2*NE+idx] + fbuf[5*NE+idx] + fbuf[8*NE+idx] + fbuf[11*NE+idx];
    }
    F[3*n+0] = -gx; F[3*n+1] = -gy; F[3*n+2] = -gz;
}

// ================= force reduce: s-side scatter (atomics) ====================
__global__ __launch_bounds__(256) void freduce_s(
    const float* __restrict__ fbuf, const int* __restrict__ eidx,
    const int* __restrict__ elist, float* __restrict__ F)
{
    int idx = blockIdx.x*256 + threadIdx.x;
    if (idx >= NE) return;
    int e = elist[idx];
    int s = eidx[e];
    float gx = fbuf[0*NE+idx] + fbuf[3*NE+idx] + fbuf[6*NE+idx] + fbuf[ 9*NE+idx];
    float gy = fbuf[1*NE+idx] + fbuf[4*NE+idx] + fbuf[7*NE+idx] + fbuf[10*NE+idx];
    float gz = fbuf[2*NE+idx] + fbuf[5*NE+idx] + fbuf[8*NE+idx] + fbuf[11*NE+idx];
    atomicAdd(&F[3*s+0], gx); atomicAdd(&F[3*s+1], gy); atomicAdd(&F[3*s+2], gz);
}

// ================= fallback: round-1 atomic edge forward =====================
__global__ __launch_bounds__(256) void edge_fwd_fb(
    const float* __restrict__ pos, const int* __restrict__ eidx,
    const float* __restrict__ shifts, const int* __restrict__ species,
    const float* __restrict__ Wz,
    const float* __restrict__ rW1, const float* __restrict__ rb1,
    const float* __restrict__ rW2, const float* __restrict__ rb2,
    const float* __restrict__ rW3, const float* __restrict__ rb3,
    float* __restrict__ A_t)
{
    const int e = blockIdx.x*256 + threadIdx.x;
    const int l = blockIdx.y;
    if (e >= NE) return;
    const int s = eidx[e];
    const int t = eidx[NE + e];
    float vx = pos[3*t+0]-pos[3*s+0]+shifts[3*e+0];
    float vy = pos[3*t+1]-pos[3*s+1]+shifts[3*e+1];
    float vz = pos[3*t+2]-pos[3*s+2]+shifts[3*e+2];
    float r2 = vx*vx+vy*vy+vz*vz + FEPS;
    float r  = sqrtf(r2);
    float inv_r = 1.0f/r;
    float x = vx*inv_r, y = vy*inv_r, z = vz*inv_r;
    float tt = r*(1.0f/RCUT);
    float fcv = 0.0f;
    if (r < RCUT){
        float t2=tt*tt, t3=t2*tt, t6=t3*t3;
        fcv = 1.0f + t6*(-28.0f + tt*(48.0f - 21.0f*tt));
    }
    float inv_rp = 1.0f/(r+FEPS);
    float w = PREF*fcv*inv_rp;
    float s1,c1; __sincosf(PI_R*r, &s1, &c1);
    float xr[8];
    {
        float sp_=0.f, sc=s1; const float c2=2.f*c1;
        #pragma unroll
        for(int m=0;m<8;m++){ xr[m]=sc*w; float nx=c2*sc-sp_; sp_=sc; sc=nx; }
    }
    const float* W1 = rW1 + l*256;  const float* B1 = rb1 + l*32;
    float h1[32];
    #pragma unroll
    for(int k=0;k<32;k++){
        float a = B1[k];
        #pragma unroll
        for(int q=0;q<8;q++) a += xr[q]*W1[k*8+q];
        h1[k] = a*sigm(a);
    }
    const float* W2 = rW2 + l*1024; const float* B2 = rb2 + l*32;
    float h2[32];
    #pragma unroll
    for(int j=0;j<32;j++){
        float a = B2[j];
        #pragma unroll
        for(int k=0;k<32;k++) a += h1[k]*W2[j*32+k];
        h2[j] = a*sigm(a);
    }
    const float* W3 = rW3 + l*1024; const float* B3 = rb3 + l*32;
    const int sp = species[s];
    float RlZ[32];
    #pragma unroll
    for(int j=0;j<32;j++){
        float a = B3[j];
        #pragma unroll
        for(int k=0;k<32;k++) a += h2[k]*W3[j*32+k];
        RlZ[j] = a * Wz[j*3+sp];
    }
    #define ACCI(I, YV) { const float yv=(YV); \
        _Pragma("unroll") \
        for(int k=0;k<32;k++) atomicAdd(&A_t[((I)*32+k)*NN + t], RlZ[k]*yv); }
    if (l==0){
        ACCI(0, 1.0f)
    } else if (l==1){
        ACCI(1, 1.7320508f*x) ACCI(2, 1.7320508f*y) ACCI(3, 1.7320508f*z)
    } else if (l==2){
        ACCI(4, 3.8729833f*x*y) ACCI(5, 3.8729833f*y*z)
        ACCI(6, 1.1180340f*(3.f*z*z-1.f)) ACCI(7, 3.8729833f*x*z)
        ACCI(8, 1.9364917f*(x*x-y*y))
    } else {
        ACCI(9,  2.0916501f*y*(3.f*x*x-y*y))
        ACCI(10, 10.246951f*x*y*z)
        ACCI(11, 1.6201852f*y*(5.f*z*z-1.f))
        ACCI(12, 1.3228757f*(5.f*z*z*z-3.f*z))
        ACCI(13, 1.6201852f*x*(5.f*z*z-1.f))
        ACCI(14, 5.1234754f*z*(x*x-y*y))
        ACCI(15, 2.0916501f*x*(x*x-3.f*y*y))
    }
    #undef ACCI
}

// ================= launcher =================
extern "C" void kernel_launch(void* const* d_in, const int* in_sizes, int n_in,
                              void* d_out, int out_size, void* d_ws, size_t ws_size,
                              hipStream_t stream)
{
    const float* pos    = (const float*)d_in[0];
    const int*   eidx   = (const int*)  d_in[1];
    const float* shifts = (const float*)d_in[2];
    const int*   spec   = (const int*)  d_in[3];
    const int*   batch  = (const int*)  d_in[4];
    const float* Wz     = (const float*)d_in[5];
    const float* rW1    = (const float*)d_in[6];
    const float* rb1    = (const float*)d_in[7];
    const float* rW2    = (const float*)d_in[8];
    const float* rb2    = (const float*)d_in[9];
    const float* rW3    = (const float*)d_in[10];
    const float* rb3    = (const float*)d_in[11];
    const float* mixW   = (const float*)d_in[12];
    const float* symW1  = (const float*)d_in[13];
    const float* symW2  = (const float*)d_in[14];
    const float* eW     = (const float*)d_in[15];
    const float* ebp    = (const float*)d_in[16];
    const float* e0W    = (const float*)d_in[17];
    const float* e0b    = (const float*)d_in[18];
    float* out = (float*)d_out;

    // workspace: ints [deg NN | roff NN+1 | woff NN | elist NE], then floats
    // [A_t 512*NN | E_node NN | fbuf 12*NE | msg 144*NE]
    // einv (NE ints) aliases fbuf; dA_n (512*NN) aliases msg
    const size_t INTS   = (size_t)(3*NN + 1 + NE);
    const size_t FOFF   = ((INTS*4 + 255)/256)*256;
    const size_t NEEDED = FOFF + ((size_t)512*NN + NN + (size_t)12*NE + (size_t)144*NE)*4;

    if (ws_size >= NEEDED){
        int*   deg    = (int*)d_ws;
        int*   roff   = deg + NN;
        int*   woff   = roff + NN + 1;
        int*   elist  = woff + NN;
        float* f0     = (float*)((char*)d_ws + FOFF);
        float* A_t    = f0;
        float* E_node = A_t + (size_t)512*NN;
        float* fbuf   = E_node + NN;
        float* msg    = fbuf + (size_t)12*NE;
        float* dA_n   = msg;            // alias: msg dead after gather
        int*   einv   = (int*)fbuf;     // alias: einv dead before fbuf written

        hipMemsetAsync(deg, 0, NN*sizeof(int), stream);
        hipMemsetAsync(E_node, 0, NN*sizeof(float), stream);
        hipMemsetAsync(d_out, 0, (size_t)out_size*sizeof(float), stream);

        csr_count  <<<(NE+255)/256, 256, 0, stream>>>(eidx, deg);
        csr_scan   <<<1, 256, 0, stream>>>(deg, roff, woff);
        csr_scatter<<<(NE+255)/256, 256, 0, stream>>>(eidx, woff, elist, einv);
        edge_compute<<<(NE+255)/256, 256, 0, stream>>>(pos, eidx, shifts, spec, Wz,
                                                       rW1, rb1, rW2, rb2, rW3, rb3,
                                                       einv, msg);
        gather<<<(NN*64+255)/256, 256, 0, stream>>>(msg, roff, A_t);
        dim3 ng((NN+255)/256, 16);
        node_pass<true><<<ng, 256, 0, stream>>>(A_t, spec, mixW, symW1, symW2,
                                                eW, ebp, e0W, e0b, dA_n, E_node);
        ereduce<<<(NN+255)/256, 256, 0, stream>>>(E_node, batch, out);
        edge_bwd<true><<<NXB*4, 256, 0, stream>>>(pos, eidx, shifts, spec, Wz,
                                                  rW1, rb1, rW2, rb2, rW3, rb3,
                                                  dA_n, elist, fbuf);
        freduce_t<<<(NN+255)/256, 256, 0, stream>>>(fbuf, roff, out + NG);
        freduce_s<<<(NE+255)/256, 256, 0, stream>>>(fbuf, eidx, elist, out + NG);
    } else {
        // fallback: round-1 path (requires 41 MB, known-good)
        float* A_t    = (float*)d_ws;
        float* E_node = A_t + (size_t)512*NN;
        float* dA_t   = E_node + NN;
        hipMemsetAsync(d_ws, 0, ((size_t)512*NN + NN)*sizeof(float), stream);
        hipMemsetAsync(d_out, 0, (size_t)out_size*sizeof(float), stream);
        dim3 eg((NE+255)/256, 4);
        edge_fwd_fb<<<eg, 256, 0, stream>>>(pos, eidx, shifts, spec, Wz,
                                            rW1, rb1, rW2, rb2, rW3, rb3, A_t);
        dim3 ng((NN+255)/256, 16);
        node_pass<false><<<ng, 256, 0, stream>>>(A_t, spec, mixW, symW1, symW2,
                                                 eW, ebp, e0W, e0b, dA_t, E_node);
        ereduce<<<(NN+255)/256, 256, 0, stream>>>(E_node, batch, out);
        dim3 eg2((NE+255)/256, 4);
        edge_bwd<false><<<eg2, 256, 0, stream>>>(pos, eidx, shifts, spec, Wz,
                                                 rW1, rb1, rW2, rb2, rW3, rb3,
                                                 dA_t, nullptr, out + NG);
    }
}

// Round 13
// 634.710 us; speedup vs baseline: 2.0447x; 1.0090x over previous
//
#include <hip/hip_runtime.h>

#define NN 10000
#define NE 100000
#define NG 64
#define RCUT 5.0f
#define FEPS 1e-9f
#define PREF 0.63245553203367586f   /* sqrt(2/RCUT) */
#define PI_R 0.62831853071795864f   /* pi/RCUT */
#define INVK 0.17677669529663687f   /* 1/sqrt(32) */
#define NXB ((NE+255)/256)          /* 391 */

static __device__ __forceinline__ float sigm(float z){ return 1.0f/(1.0f+__expf(-z)); }

// ================= CSR build =================
__global__ __launch_bounds__(256) void csr_count(const int* __restrict__ eidx,
                                                 int* __restrict__ deg)
{
    int e = blockIdx.x*256 + threadIdx.x;
    if (e < NE) atomicAdd(&deg[eidx[NE + e]], 1);
}

__global__ __launch_bounds__(256) void csr_scan(const int* __restrict__ deg,
                                                int* __restrict__ roff,
                                                int* __restrict__ woff)
{
    __shared__ int part[256];
    const int tid = threadIdx.x;
    const int C = 40;                 // 256*40 = 10240 >= NN
    int base = tid*C;
    int s = 0;
    for (int j=0;j<C;j++){ int idx=base+j; if (idx<NN) s += deg[idx]; }
    part[tid] = s; __syncthreads();
    for (int off=1; off<256; off<<=1){
        int v = part[tid];
        int add = (tid>=off) ? part[tid-off] : 0;
        __syncthreads();
        part[tid] = v + add;
        __syncthreads();
    }
    int run = (tid==0) ? 0 : part[tid-1];
    for (int j=0;j<C;j++){
        int idx = base+j;
        if (idx < NN){ roff[idx]=run; woff[idx]=run; run += deg[idx]; }
    }
    if (tid==255) roff[NN] = run;
}

__global__ __launch_bounds__(256) void csr_scatter(const int* __restrict__ eidx,
                                                   int* __restrict__ woff,
                                                   int* __restrict__ elist,
                                                   int* __restrict__ einv)
{
    int e = blockIdx.x*256 + threadIdx.x;
    if (e < NE){
        int pos = atomicAdd(&woff[eidx[NE + e]], 1);
        elist[pos] = e;
        einv[e] = pos;
    }
}

// ================= per-edge forward: msg records (CSR slot order) ============
__global__ __launch_bounds__(256) void edge_compute(
    const float* __restrict__ pos, const int* __restrict__ eidx,
    const float* __restrict__ shifts, const int* __restrict__ species,
    const float* __restrict__ Wz,
    const float* __restrict__ rW1, const float* __restrict__ rb1,
    const float* __restrict__ rW2, const float* __restrict__ rb2,
    const float* __restrict__ rW3, const float* __restrict__ rb3,
    const int* __restrict__ einv, float* __restrict__ msg)
{
    const int e = blockIdx.x*256 + threadIdx.x;
    if (e >= NE) return;
    const int s = eidx[e];
    const int t = eidx[NE + e];
    float vx = pos[3*t+0]-pos[3*s+0]+shifts[3*e+0];
    float vy = pos[3*t+1]-pos[3*s+1]+shifts[3*e+1];
    float vz = pos[3*t+2]-pos[3*s+2]+shifts[3*e+2];
    float r2 = vx*vx+vy*vy+vz*vz + FEPS;
    float r  = sqrtf(r2);
    float inv_r = 1.0f/r;
    float x = vx*inv_r, y = vy*inv_r, z = vz*inv_r;

    float tt = r*(1.0f/RCUT);
    float fc = 0.0f;
    if (r < RCUT){
        float t2=tt*tt, t3=t2*tt, t6=t3*t3;
        fc = 1.0f + t6*(-28.0f + tt*(48.0f - 21.0f*tt));
    }
    float inv_rp = 1.0f/(r+FEPS);
    float w = PREF*fc*inv_rp;
    float s1,c1; __sincosf(PI_R*r, &s1, &c1);
    float xr[8];
    {
        float sp_=0.f, sc=s1; const float c2=2.f*c1;
        #pragma unroll
        for(int m=0;m<8;m++){ xr[m]=sc*w; float nx=c2*sc-sp_; sp_=sc; sc=nx; }
    }
    const int sp = species[s];
    float* mb = msg + (size_t)einv[e]*144;
    #pragma unroll
    for (int l=0;l<4;l++){
        const float* W1 = rW1 + l*256;  const float* B1 = rb1 + l*32;
        float h1[32];
        #pragma unroll
        for(int k=0;k<32;k++){
            float a = B1[k];
            #pragma unroll
            for(int q=0;q<8;q++) a += xr[q]*W1[k*8+q];
            h1[k] = a*sigm(a);
        }
        const float* W2 = rW2 + l*1024; const float* B2 = rb2 + l*32;
        float h2[32];
        #pragma unroll
        for(int j=0;j<32;j++){
            float a = B2[j];
            #pragma unroll
            for(int k=0;k<32;k++) a += h1[k]*W2[j*32+k];
            h2[j] = a*sigm(a);
        }
        const float* W3 = rW3 + l*1024; const float* B3 = rb3 + l*32;
        #pragma unroll
        for(int j=0;j<32;j++){
            float a = B3[j];
            #pragma unroll
            for(int k=0;k<32;k++) a += h2[k]*W3[j*32+k];
            mb[l*32+j] = a * Wz[j*3+sp];
        }
    }
    float* Yp = mb + 128;
    Yp[0]  = 1.0f;
    Yp[1]  = 1.7320508f*x;  Yp[2]  = 1.7320508f*y;  Yp[3]  = 1.7320508f*z;
    Yp[4]  = 3.8729833f*x*y; Yp[5] = 3.8729833f*y*z;
    Yp[6]  = 1.1180340f*(3.f*z*z-1.f);
    Yp[7]  = 3.8729833f*x*z; Yp[8] = 1.9364917f*(x*x-y*y);
    Yp[9]  = 2.0916501f*y*(3.f*x*x-y*y);
    Yp[10] = 10.246951f*x*y*z;
    Yp[11] = 1.6201852f*y*(5.f*z*z-1.f);
    Yp[12] = 1.3228757f*(5.f*z*z*z-3.f*z);
    Yp[13] = 1.6201852f*x*(5.f*z*z-1.f);
    Yp[14] = 5.1234754f*z*(x*x-y*y);
    Yp[15] = 2.0916501f*x*(x*x-3.f*y*y);
}

// ================= gather: one wave per node, sequential msg stream ==========
__global__ __launch_bounds__(256) void gather(
    const float* __restrict__ msg, const int* __restrict__ roff,
    float* __restrict__ A_t)
{
    const int w = (blockIdx.x*256 + threadIdx.x) >> 6;   // node id
    const int lane = threadIdx.x & 63;
    if (w >= NN) return;
    const int k = lane & 31;
    const bool hi = (lane >= 32);
    float a0=0,a1=0,a2=0,a3=0,a4=0,a5=0,a6=0,a7=0;
    const int beg = roff[w], end = roff[w+1];
    for (int idx=beg; idx<end; ++idx){
        const float* b = msg + (size_t)idx*144;
        float rl1 = b[32+k];
        float rl2 = b[64+k];
        float rl3 = b[96+k];
        const float* Yp = b + 128;
        if (!hi){
            float rl0 = b[k];
            a0 += rl0;
            a1 += rl1*Yp[2];
            a2 += rl2*Yp[4];
            a3 += rl2*Yp[6];
            a4 += rl2*Yp[8];
            a5 += rl3*Yp[10];
            a6 += rl3*Yp[12];
            a7 += rl3*Yp[14];
        } else {
            a0 += rl1*Yp[1];
            a1 += rl1*Yp[3];
            a2 += rl2*Yp[5];
            a3 += rl2*Yp[7];
            a4 += rl3*Yp[9];
            a5 += rl3*Yp[11];
            a6 += rl3*Yp[13];
            a7 += rl3*Yp[15];
        }
    }
    const int i0 = hi ? 1 : 0;
    A_t[((i0+ 0)*32+k)*NN + w] = a0;
    A_t[((i0+ 2)*32+k)*NN + w] = a1;
    A_t[((i0+ 4)*32+k)*NN + w] = a2;
    A_t[((i0+ 6)*32+k)*NN + w] = a3;
    A_t[((i0+ 8)*32+k)*NN + w] = a4;
    A_t[((i0+10)*32+k)*NN + w] = a5;
    A_t[((i0+12)*32+k)*NN + w] = a6;
    A_t[((i0+14)*32+k)*NN + w] = a7;
}

// ================= node pass =================
template<bool NM>
__global__ __launch_bounds__(256) void node_pass(
    const float* __restrict__ A_t, const int* __restrict__ species,
    const float* __restrict__ mixW, const float* __restrict__ symW1,
    const float* __restrict__ symW2, const float* __restrict__ eW,
    const float* __restrict__ ebp, const float* __restrict__ e0W,
    const float* __restrict__ e0b,
    float* __restrict__ dA, float* __restrict__ E_node)
{
    const int n = blockIdx.x*256 + threadIdx.x;
    const int i = blockIdx.y;
    const int l = (i==0)?0 : (i<4)?1 : (i<9)?2 : 3;
    if (n >= NN) return;
    const int sp = species[n];

    float a[32];
    #pragma unroll
    for(int k=0;k<32;k++) a[k] = A_t[(i*32+k)*NN + n];

    const float* M = mixW + l*1024;
    float A2[32];
    #pragma unroll
    for(int o=0;o<32;o++){
        float acc = 0.f;
        #pragma unroll
        for(int k=0;k<32;k++) acc += a[k]*M[o*32+k];
        A2[o] = acc*INVK;
    }
    const float nl = (l==0)?1.0f : (l==1)?0.57735027f : (l==2)?0.44721360f : 0.37796447f;
    float ce = 0.f;
    float dA2[32];
    #pragma unroll
    for(int o=0;o<32;o++){
        float w2v = symW2[(sp*4+l)*32+o];
        float ew  = eW[o];
        float c = A2[o]*A2[o]*nl*w2v;
        float g = 2.f*A2[o]*nl*w2v;
        if (i==0){ float w1v = symW1[sp*32+o]; c += w1v*A2[o]; g += w1v; }
        ce += c*ew;
        dA2[o] = g*ew;
    }
    if (i==0) ce += ebp[0] + e0W[sp] + e0b[0];

    #pragma unroll
    for(int k=0;k<32;k++){
        float acc = 0.f;
        #pragma unroll
        for(int o=0;o<32;o++) acc += dA2[o]*M[o*32+k];
        if (NM) dA[(size_t)n*512 + i*32 + k] = acc*INVK;
        else    dA[(i*32+k)*NN + n]          = acc*INVK;
    }
    atomicAdd(&E_node[n], ce);
}

// ================= E binning (batch sorted -> wave-segmented reduce) =========
__global__ __launch_bounds__(256) void ereduce(
    const float* __restrict__ E_node, const int* __restrict__ batch,
    float* __restrict__ out)
{
    int n = blockIdx.x*256 + threadIdx.x;
    const int lane = threadIdx.x & 63;
    float v = (n < NN) ? E_node[n] : 0.f;
    int   b = (n < NN) ? batch[n]  : -1;
    #pragma unroll
    for (int d=1; d<64; d<<=1){
        float pv = __shfl_down(v, d, 64);
        int   pb = __shfl_down(b, d, 64);
        if ((lane + d) < 64 && pb == b) v += pv;
    }
    int prevb = __shfl_up(b, 1, 64);
    if (n < NN && (lane == 0 || prevb != b)) atomicAdd(&out[b], v);
}

// ================= edge backward (per-l planes, XCD swizzle, LDS weights) ====
// Weights staged in LDS (row-major + transposed), swept as float2
// (ds_read_b64) with two partial accumulators — halves DS instruction count
// vs scalar (round-12: 4608 ds_read_b32 => DS-issue-bound at 312 us).
// float4 form spilled (rounds 10/11); float2 keeps the proven stage state.
template<bool NM>
__global__ __launch_bounds__(256) void edge_bwd(
    const float* __restrict__ pos, const int* __restrict__ eidx,
    const float* __restrict__ shifts, const int* __restrict__ species,
    const float* __restrict__ Wz,
    const float* __restrict__ rW1, const float* __restrict__ rb1,
    const float* __restrict__ rW2, const float* __restrict__ rb2,
    const float* __restrict__ rW3, const float* __restrict__ rb3,
    const float* __restrict__ dA, const int* __restrict__ elist,
    float* __restrict__ fout)
{
    __shared__ __align__(8) float W1L[256], W1T[256];
    __shared__ __align__(8) float W2L[1024], W2T[1024];
    __shared__ __align__(8) float W3L[1024], W3T[1024];
    __shared__ float B1L[32], B2L[32], B3L[32], WzL[96];

    int xb, l;
    if (NM){
        const int nwg = NXB*4;            // 1564
        const int q = nwg/8, r = nwg%8;   // 195, 4
        const int bid = blockIdx.x;
        const int xcd = bid & 7, p = bid >> 3;
        const int g = (xcd < r ? xcd*(q+1) : r*(q+1) + (xcd-r)*q) + p;
        xb = g >> 2; l = g & 3;
    } else {
        xb = blockIdx.x; l = blockIdx.y;
    }
    const int tid = threadIdx.x;
    {
        const float* W1g = rW1 + l*256;
        const float* W2g = rW2 + l*1024;
        const float* W3g = rW3 + l*1024;
        { float v = W1g[tid]; W1L[tid] = v; W1T[(tid&7)*32 + (tid>>3)] = v; }
        #pragma unroll
        for (int i0=0;i0<4;i0++){
            int i = i0*256 + tid;
            float v2 = W2g[i]; W2L[i] = v2; W2T[(i&31)*32 + (i>>5)] = v2;
            float v3 = W3g[i]; W3L[i] = v3; W3T[(i&31)*32 + (i>>5)] = v3;
        }
        if (tid < 32){ B1L[tid] = rb1[l*32+tid]; B2L[tid] = rb2[l*32+tid];
                       B3L[tid] = rb3[l*32+tid]; }
        if (tid < 96) WzL[tid] = Wz[tid];
    }
    __syncthreads();

    const int idx = xb*256 + tid;
    if (idx >= NE) return;
    const int e = NM ? elist[idx] : idx;
    const int s = eidx[e];
    const int t = eidx[NE + e];
    float vx = pos[3*t+0]-pos[3*s+0]+shifts[3*e+0];
    float vy = pos[3*t+1]-pos[3*s+1]+shifts[3*e+1];
    float vz = pos[3*t+2]-pos[3*s+2]+shifts[3*e+2];
    float r2 = vx*vx+vy*vy+vz*vz + FEPS;
    float r  = sqrtf(r2);
    float inv_r = 1.0f/r;
    float x = vx*inv_r, y = vy*inv_r, z = vz*inv_r;

    float tt = r*(1.0f/RCUT);
    float fc = 0.0f, dfc = 0.0f;
    if (r < RCUT){
        float t2=tt*tt, t3=t2*tt, t5=t3*t2, t6=t5*tt, t7=t6*tt;
        fc  = 1.0f + t6*(-28.0f + tt*(48.0f - 21.0f*tt));
        dfc = (-168.f*t5 + 336.f*t6 - 168.f*t7)*(1.0f/RCUT);
    }
    float inv_rp = 1.0f/(r+FEPS);
    float w = PREF*fc*inv_rp;
    float s1,c1; __sincosf(PI_R*r, &s1, &c1);
    float sn[8], cn[8];
    {
        float sp_=0.f, sc=s1, cp_=1.f, cc=c1; const float c2=2.f*c1;
        #pragma unroll
        for(int m=0;m<8;m++){
            sn[m]=sc; cn[m]=cc;
            float nx=c2*sc-sp_; sp_=sc; sc=nx;
            float ncx=c2*cc-cp_; cp_=cc; cc=ncx;
        }
    }

    // 32-dot against a float2 LDS row, two accumulator chains
    #define DOT32F2(ROWPTR, VEC, OUT) { \
        const float2* _row = (const float2*)(ROWPTR); \
        float _a0=0.f,_a1=0.f; \
        _Pragma("unroll") \
        for(int _c=0;_c<16;_c++){ \
            float2 _rv = _row[_c]; \
            _a0 += (VEC)[2*_c+0]*_rv.x; _a1 += (VEC)[2*_c+1]*_rv.y; } \
        OUT = _a0+_a1; }

    // forward, keeping silu-derivative factors (float2 LDS reads)
    float df1[32], h1[32];
    {
        float xr[8];
        #pragma unroll
        for(int q=0;q<8;q++) xr[q] = sn[q]*w;
        #pragma unroll
        for(int k=0;k<32;k++){
            const float2* row = (const float2*)&W1L[k*8];
            float2 u0=row[0], u1=row[1], u2=row[2], u3=row[3];
            float a = B1L[k]
                + (xr[0]*u0.x + xr[1]*u0.y + xr[2]*u1.x + xr[3]*u1.y)
                + (xr[4]*u2.x + xr[5]*u2.y + xr[6]*u3.x + xr[7]*u3.y);
            float sg=sigm(a); h1[k]=a*sg; df1[k]=sg*(1.f + a*(1.f-sg));
        }
    }
    float df2[32], h2[32];
    #pragma unroll
    for(int j=0;j<32;j++){
        float o; DOT32F2(&W2L[j*32], h1, o);
        float a = B2L[j] + o;
        float sg=sigm(a); h2[j]=a*sg; df2[j]=sg*(1.f + a*(1.f-sg));
    }
    const int sp = species[s];
    float RlZ[32];
    #pragma unroll
    for(int j=0;j<32;j++){
        float o; DOT32F2(&W3L[j*32], h2, o);
        RlZ[j] = (B3L[j] + o) * WzL[j*3+sp];
    }
    float dRlZ[32];
    #pragma unroll
    for(int k=0;k<32;k++) dRlZ[k]=0.f;
    float dux=0.f, duy=0.f, duz=0.f;
    #define ROW(I, YV, DX, DY, DZ) { \
        const float yv=(YV); float dY=0.f; \
        _Pragma("unroll") \
        for(int k=0;k<32;k++){ \
            float g = NM ? dA[(size_t)t*512 + (I)*32 + k] : dA[((I)*32+k)*NN + t]; \
            dRlZ[k] += g*yv; dY += g*RlZ[k]; } \
        dux += dY*(DX); duy += dY*(DY); duz += dY*(DZ); }
    if (l==0){
        ROW(0, 1.0f, 0.f,0.f,0.f)
    } else if (l==1){
        ROW(1, 1.7320508f*x, 1.7320508f, 0.f, 0.f)
        ROW(2, 1.7320508f*y, 0.f, 1.7320508f, 0.f)
        ROW(3, 1.7320508f*z, 0.f, 0.f, 1.7320508f)
    } else if (l==2){
        ROW(4, 3.8729833f*x*y, 3.8729833f*y, 3.8729833f*x, 0.f)
        ROW(5, 3.8729833f*y*z, 0.f, 3.8729833f*z, 3.8729833f*y)
        ROW(6, 1.1180340f*(3.f*z*z-1.f), 0.f, 0.f, 6.7082039f*z)
        ROW(7, 3.8729833f*x*z, 3.8729833f*z, 0.f, 3.8729833f*x)
        ROW(8, 1.9364917f*(x*x-y*y), 3.8729833f*x, -3.8729833f*y, 0.f)
    } else {
        ROW(9,  2.0916501f*y*(3.f*x*x-y*y), 12.549901f*x*y, 2.0916501f*(3.f*x*x-3.f*y*y), 0.f)
        ROW(10, 10.246951f*x*y*z, 10.246951f*y*z, 10.246951f*x*z, 10.246951f*x*y)
        ROW(11, 1.6201852f*y*(5.f*z*z-1.f), 0.f, 1.6201852f*(5.f*z*z-1.f), 16.201852f*y*z)
        ROW(12, 1.3228757f*(5.f*z*z*z-3.f*z), 0.f, 0.f, 1.3228757f*(15.f*z*z-3.f))
        ROW(13, 1.6201852f*x*(5.f*z*z-1.f), 1.6201852f*(5.f*z*z-1.f), 0.f, 16.201852f*x*z)
        ROW(14, 5.1234754f*z*(x*x-y*y), 10.246951f*x*z, -10.246951f*y*z, 5.1234754f*(x*x-y*y))
        ROW(15, 2.0916501f*x*(x*x-3.f*y*y), 2.0916501f*(3.f*x*x-3.f*y*y), -12.549901f*x*y, 0.f)
    }
    #undef ROW
    #pragma unroll
    for(int j=0;j<32;j++) dRlZ[j] *= WzL[j*3+sp];
    float dz2[32];
    #pragma unroll
    for(int k=0;k<32;k++){
        float o; DOT32F2(&W3T[k*32], dRlZ, o);
        dz2[k] = o*df2[k];
    }
    float dz1[32];
    #pragma unroll
    for(int k=0;k<32;k++){
        float o; DOT32F2(&W2T[k*32], dz2, o);
        dz1[k] = o*df1[k];
    }
    float gr = 0.f;
    #pragma unroll
    for(int m=0;m<8;m++){
        float o; DOT32F2(&W1T[m*32], dz1, o);
        float b  = PREF*sn[m]*inv_rp;
        float db = PREF*((float)(m+1)*PI_R*cn[m]*(r+FEPS) - sn[m])*inv_rp*inv_rp;
        gr += o*(db*fc + b*dfc);
    }
    #undef DOT32F2
    float udd = x*dux + y*duy + z*duz;
    float gx = gr*x + (dux - x*udd)*inv_r;
    float gy = gr*y + (duy - y*udd)*inv_r;
    float gz = gr*z + (duz - z*udd)*inv_r;
    if (NM){
        fout[(l*3+0)*NE + idx] = gx;
        fout[(l*3+1)*NE + idx] = gy;
        fout[(l*3+2)*NE + idx] = gz;
    } else {
        atomicAdd(&fout[3*t+0], -gx); atomicAdd(&fout[3*t+1], -gy); atomicAdd(&fout[3*t+2], -gz);
        atomicAdd(&fout[3*s+0],  gx); atomicAdd(&fout[3*s+1],  gy); atomicAdd(&fout[3*s+2],  gz);
    }
}

// ================= force reduce: t-side gather (no atomics) ==================
__global__ __launch_bounds__(256) void freduce_t(
    const float* __restrict__ fbuf, const int* __restrict__ roff,
    float* __restrict__ F)
{
    int n = blockIdx.x*256 + threadIdx.x;
    if (n >= NN) return;
    float gx=0.f, gy=0.f, gz=0.f;
    const int beg = roff[n], end = roff[n+1];
    for (int idx=beg; idx<end; ++idx){
        gx += fbuf[0*NE+idx] + fbuf[3*NE+idx] + fbuf[6*NE+idx] + fbuf[ 9*NE+idx];
        gy += fbuf[1*NE+idx] + fbuf[4*NE+idx] + fbuf[7*NE+idx] + fbuf[10*NE+idx];
        gz += fbuf[2*NE+idx] + fbuf[5*NE+idx] + fbuf[8*NE+idx] + fbuf[11*NE+idx];
    }
    F[3*n+0] = -gx; F[3*n+1] = -gy; F[3*n+2] = -gz;
}

// ================= force reduce: s-side scatter (atomics) ====================
__global__ __launch_bounds__(256) void freduce_s(
    const float* __restrict__ fbuf, const int* __restrict__ eidx,
    const int* __restrict__ elist, float* __restrict__ F)
{
    int idx = blockIdx.x*256 + threadIdx.x;
    if (idx >= NE) return;
    int e = elist[idx];
    int s = eidx[e];
    float gx = fbuf[0*NE+idx] + fbuf[3*NE+idx] + fbuf[6*NE+idx] + fbuf[ 9*NE+idx];
    float gy = fbuf[1*NE+idx] + fbuf[4*NE+idx] + fbuf[7*NE+idx] + fbuf[10*NE+idx];
    float gz = fbuf[2*NE+idx] + fbuf[5*NE+idx] + fbuf[8*NE+idx] + fbuf[11*NE+idx];
    atomicAdd(&F[3*s+0], gx); atomicAdd(&F[3*s+1], gy); atomicAdd(&F[3*s+2], gz);
}

// ================= fallback: round-1 atomic edge forward =====================
__global__ __launch_bounds__(256) void edge_fwd_fb(
    const float* __restrict__ pos, const int* __restrict__ eidx,
    const float* __restrict__ shifts, const int* __restrict__ species,
    const float* __restrict__ Wz,
    const float* __restrict__ rW1, const float* __restrict__ rb1,
    const float* __restrict__ rW2, const float* __restrict__ rb2,
    const float* __restrict__ rW3, const float* __restrict__ rb3,
    float* __restrict__ A_t)
{
    const int e = blockIdx.x*256 + threadIdx.x;
    const int l = blockIdx.y;
    if (e >= NE) return;
    const int s = eidx[e];
    const int t = eidx[NE + e];
    float vx = pos[3*t+0]-pos[3*s+0]+shifts[3*e+0];
    float vy = pos[3*t+1]-pos[3*s+1]+shifts[3*e+1];
    float vz = pos[3*t+2]-pos[3*s+2]+shifts[3*e+2];
    float r2 = vx*vx+vy*vy+vz*vz + FEPS;
    float r  = sqrtf(r2);
    float inv_r = 1.0f/r;
    float x = vx*inv_r, y = vy*inv_r, z = vz*inv_r;
    float tt = r*(1.0f/RCUT);
    float fcv = 0.0f;
    if (r < RCUT){
        float t2=tt*tt, t3=t2*tt, t6=t3*t3;
        fcv = 1.0f + t6*(-28.0f + tt*(48.0f - 21.0f*tt));
    }
    float inv_rp = 1.0f/(r+FEPS);
    float w = PREF*fcv*inv_rp;
    float s1,c1; __sincosf(PI_R*r, &s1, &c1);
    float xr[8];
    {
        float sp_=0.f, sc=s1; const float c2=2.f*c1;
        #pragma unroll
        for(int m=0;m<8;m++){ xr[m]=sc*w; float nx=c2*sc-sp_; sp_=sc; sc=nx; }
    }
    const float* W1 = rW1 + l*256;  const float* B1 = rb1 + l*32;
    float h1[32];
    #pragma unroll
    for(int k=0;k<32;k++){
        float a = B1[k];
        #pragma unroll
        for(int q=0;q<8;q++) a += xr[q]*W1[k*8+q];
        h1[k] = a*sigm(a);
    }
    const float* W2 = rW2 + l*1024; const float* B2 = rb2 + l*32;
    float h2[32];
    #pragma unroll
    for(int j=0;j<32;j++){
        float a = B2[j];
        #pragma unroll
        for(int k=0;k<32;k++) a += h1[k]*W2[j*32+k];
        h2[j] = a*sigm(a);
    }
    const float* W3 = rW3 + l*1024; const float* B3 = rb3 + l*32;
    const int sp = species[s];
    float RlZ[32];
    #pragma unroll
    for(int j=0;j<32;j++){
        float a = B3[j];
        #pragma unroll
        for(int k=0;k<32;k++) a += h2[k]*W3[j*32+k];
        RlZ[j] = a * Wz[j*3+sp];
    }
    #define ACCI(I, YV) { const float yv=(YV); \
        _Pragma("unroll") \
        for(int k=0;k<32;k++) atomicAdd(&A_t[((I)*32+k)*NN + t], RlZ[k]*yv); }
    if (l==0){
        ACCI(0, 1.0f)
    } else if (l==1){
        ACCI(1, 1.7320508f*x) ACCI(2, 1.7320508f*y) ACCI(3, 1.7320508f*z)
    } else if (l==2){
        ACCI(4, 3.8729833f*x*y) ACCI(5, 3.8729833f*y*z)
        ACCI(6, 1.1180340f*(3.f*z*z-1.f)) ACCI(7, 3.8729833f*x*z)
        ACCI(8, 1.9364917f*(x*x-y*y))
    } else {
        ACCI(9,  2.0916501f*y*(3.f*x*x-y*y))
        ACCI(10, 10.246951f*x*y*z)
        ACCI(11, 1.6201852f*y*(5.f*z*z-1.f))
        ACCI(12, 1.3228757f*(5.f*z*z*z-3.f*z))
        ACCI(13, 1.6201852f*x*(5.f*z*z-1.f))
        ACCI(14, 5.1234754f*z*(x*x-y*y))
        ACCI(15, 2.0916501f*x*(x*x-3.f*y*y))
    }
    #undef ACCI
}

// ================= launcher =================
extern "C" void kernel_launch(void* const* d_in, const int* in_sizes, int n_in,
                              void* d_out, int out_size, void* d_ws, size_t ws_size,
                              hipStream_t stream)
{
    const float* pos    = (const float*)d_in[0];
    const int*   eidx   = (const int*)  d_in[1];
    const float* shifts = (const float*)d_in[2];
    const int*   spec   = (const int*)  d_in[3];
    const int*   batch  = (const int*)  d_in[4];
    const float* Wz     = (const float*)d_in[5];
    const float* rW1    = (const float*)d_in[6];
    const float* rb1    = (const float*)d_in[7];
    const float* rW2    = (const float*)d_in[8];
    const float* rb2    = (const float*)d_in[9];
    const float* rW3    = (const float*)d_in[10];
    const float* rb3    = (const float*)d_in[11];
    const float* mixW   = (const float*)d_in[12];
    const float* symW1  = (const float*)d_in[13];
    const float* symW2  = (const float*)d_in[14];
    const float* eW     = (const float*)d_in[15];
    const float* ebp    = (const float*)d_in[16];
    const float* e0W    = (const float*)d_in[17];
    const float* e0b    = (const float*)d_in[18];
    float* out = (float*)d_out;

    const size_t INTS   = (size_t)(3*NN + 1 + NE);
    const size_t FOFF   = ((INTS*4 + 255)/256)*256;
    const size_t NEEDED = FOFF + ((size_t)512*NN + NN + (size_t)12*NE + (size_t)144*NE)*4;

    if (ws_size >= NEEDED){
        int*   deg    = (int*)d_ws;
        int*   roff   = deg + NN;
        int*   woff   = roff + NN + 1;
        int*   elist  = woff + NN;
        float* f0     = (float*)((char*)d_ws + FOFF);
        float* A_t    = f0;
        float* E_node = A_t + (size_t)512*NN;
        float* fbuf   = E_node + NN;
        float* msg    = fbuf + (size_t)12*NE;
        float* dA_n   = msg;            // alias: msg dead after gather
        int*   einv   = (int*)fbuf;     // alias: einv dead before fbuf written

        hipMemsetAsync(deg, 0, NN*sizeof(int), stream);
        hipMemsetAsync(E_node, 0, NN*sizeof(float), stream);
        hipMemsetAsync(d_out, 0, (size_t)out_size*sizeof(float), stream);

        csr_count  <<<(NE+255)/256, 256, 0, stream>>>(eidx, deg);
        csr_scan   <<<1, 256, 0, stream>>>(deg, roff, woff);
        csr_scatter<<<(NE+255)/256, 256, 0, stream>>>(eidx, woff, elist, einv);
        edge_compute<<<(NE+255)/256, 256, 0, stream>>>(pos, eidx, shifts, spec, Wz,
                                                       rW1, rb1, rW2, rb2, rW3, rb3,
                                                       einv, msg);
        gather<<<(NN*64+255)/256, 256, 0, stream>>>(msg, roff, A_t);
        dim3 ng((NN+255)/256, 16);
        node_pass<true><<<ng, 256, 0, stream>>>(A_t, spec, mixW, symW1, symW2,
                                                eW, ebp, e0W, e0b, dA_n, E_node);
        ereduce<<<(NN+255)/256, 256, 0, stream>>>(E_node, batch, out);
        edge_bwd<true><<<NXB*4, 256, 0, stream>>>(pos, eidx, shifts, spec, Wz,
                                                  rW1, rb1, rW2, rb2, rW3, rb3,
                                                  dA_n, elist, fbuf);
        freduce_t<<<(NN+255)/256, 256, 0, stream>>>(fbuf, roff, out + NG);
        freduce_s<<<(NE+255)/256, 256, 0, stream>>>(fbuf, eidx, elist, out + NG);
    } else {
        // fallback: round-1 path (requires 41 MB, known-good)
        float* A_t    = (float*)d_ws;
        float* E_node = A_t + (size_t)512*NN;
        float* dA_t   = E_node + NN;
        hipMemsetAsync(d_ws, 0, ((size_t)512*NN + NN)*sizeof(float), stream);
        hipMemsetAsync(d_out, 0, (size_t)out_size*sizeof(float), stream);
        dim3 eg((NE+255)/256, 4);
        edge_fwd_fb<<<eg, 256, 0, stream>>>(pos, eidx, shifts, spec, Wz,
                                            rW1, rb1, rW2, rb2, rW3, rb3, A_t);
        dim3 ng((NN+255)/256, 16);
        node_pass<false><<<ng, 256, 0, stream>>>(A_t, spec, mixW, symW1, symW2,
                                                 eW, ebp, e0W, e0b, dA_t, E_node);
        ereduce<<<(NN+255)/256, 256, 0, stream>>>(E_node, batch, out);
        dim3 eg2((NE+255)/256, 4);
        edge_bwd<false><<<eg2, 256, 0, stream>>>(pos, eidx, shifts, spec, Wz,
                                                 rW1, rb1, rW2, rb2, rW3, rb3,
                                                 dA_t, nullptr, out + NG);
    }
}